// Round 4
// baseline (507.447 us; speedup 1.0000x reference)
//
#include <hip/hip_runtime.h>
#include <math.h>

typedef short bf16x8 __attribute__((ext_vector_type(8)));
typedef float f32x4 __attribute__((ext_vector_type(4)));

#define S128 0.08838834764831845f   /* 1/sqrt(128) */
#define S256I 0.0625f               /* 1/sqrt(256) */
#define NN_NODES 16000

// ws layout (bytes)
#define WS_COUNTS   16448000            /* int[16000] (node arrays occupy [0,16448000)) */
#define WS_OFFSETS  (WS_COUNTS + 64000)
#define WS_CURSOR   (WS_OFFSETS + 64000)
#define WS_ORDER    (WS_CURSOR + 64000) /* int[256000] */
#define WS_W1 (WS_ORDER + 1024000)      /* W1T [128][256] bf16 UNSWIZZLED */
#define WS_W2 (WS_W1 + 65536)           /* W2T [128][128] bf16 UNSWIZZLED */
#define WS_W3 (WS_W2 + 32768)           /* W3T [128][128] bf16 UNSWIZZLED */
#define WS_WO (WS_W3 + 32768)           /* WoutT [64][128] bf16 swizzled (LDS-staged) */
#define WS_WE (WS_WO + 16384)           /* WenvT [128][128] bf16 swizzled (LDS-staged) */

// ---- host-side constant: SILU_C exactly as the reference computes it ----
static float compute_inv_silu_c() {
    double sum = 0.0, prev = 0.0;
    const double dz = 24.0 / 100000.0;
    for (int i = 0; i <= 100000; ++i) {
        double z = -12.0 + dz * (double)i;
        double pdf = exp(-0.5 * z * z) * 0.3989422804014327;
        double s = z / (1.0 + exp(-z));
        double f = s * s * pdf;
        if (i) sum += 0.5 * (prev + f) * dz;
        prev = f;
    }
    return (float)(1.0 / sqrt(sum));
}
static const float INV_SILU_C = compute_inv_silu_c();

// ---- device helpers ----
__device__ __forceinline__ unsigned int packbf(float a, float b) {
    union { float f; unsigned int u; } ca, cb;
    ca.f = a; cb.f = b;
    unsigned int ua = ca.u + (0x7fffu + ((ca.u >> 16) & 1u));
    unsigned int ub = cb.u + (0x7fffu + ((cb.u >> 16) & 1u));
    return (ua >> 16) | (ub & 0xffff0000u);
}
__device__ __forceinline__ unsigned short bf16r(float v) {
    union { float f; unsigned int u; } c; c.f = v;
    return (unsigned short)((c.u + (0x7fffu + ((c.u >> 16) & 1u))) >> 16);
}
__device__ __forceinline__ float bflo(unsigned int u) { return __uint_as_float(u << 16); }
__device__ __forceinline__ float bfhi(unsigned int u) { return __uint_as_float(u & 0xffff0000u); }
__device__ __forceinline__ int swz(int row, int b) { return b ^ ((row & 7) << 4); }
__device__ __forceinline__ float nsilu(float v, float ic) {
    return v / (1.0f + __expf(-v)) * ic;
}

// =====================================================================
// k_wprep: bf16-quantize + transpose weights into ws; zero counts[].
// W1/W2/W3 unswizzled (read direct-from-L2 as B-fragments).
// Wenv/Wout pre-swizzled (staged into LDS).
// =====================================================================
__global__ __launch_bounds__(256) void k_wprep(
    const float* __restrict__ W1, const float* __restrict__ W2,
    const float* __restrict__ W3, const float* __restrict__ Wout,
    const float* __restrict__ Wenv, char* __restrict__ wsb)
{
    const int t = blockIdx.x * 256 + threadIdx.x;   // 32768 threads
    if (t < NN_NODES) ((int*)(wsb + WS_COUNTS))[t] = 0;
    if (t < 32768) {  // W1T[128][256] unswizzled
        int n = t & 127, k = t >> 7;
        *(unsigned short*)(wsb + WS_W1 + n * 512 + k * 2) =
            bf16r(W1[k * 128 + n] * S256I);
    }
    if (t < 16384) {  // W2T, W3T [128][128] unswizzled
        int n = t & 127, k = t >> 7;
        *(unsigned short*)(wsb + WS_W2 + n * 256 + k * 2) =
            bf16r(W2[k * 128 + n] * S128);
        *(unsigned short*)(wsb + WS_W3 + n * 256 + k * 2) =
            bf16r(W3[k * 128 + n] * S128);
    }
    if (t < 16384) {  // WenvT[128][128], interleaved row perm, swizzled
        int j = t & 127, k = t >> 7;
        int c = (j & 1) ? 64 + (j >> 1) : (j >> 1);
        *(unsigned short*)(wsb + WS_WE + j * 256 + ((k * 2) ^ ((j & 7) << 4))) =
            bf16r(Wenv[k * 128 + c] * S128);
    }
    if (t < 8192) {   // WoutT[64][128] swizzled
        int o = t & 63, uu = t >> 6;
        *(unsigned short*)(wsb + WS_WO + o * 256 + ((uu * 2) ^ ((o & 7) << 4))) =
            bf16r(Wout[uu * 64 + o] * S128);
    }
}

// =====================================================================
// sort-by-sender chain
// =====================================================================
__global__ __launch_bounds__(1024) void k_hist(
    const int* __restrict__ senders, int* __restrict__ counts, int E)
{
    const int e = blockIdx.x * 1024 + threadIdx.x;
    if (e < E) atomicAdd(&counts[senders[e]], 1);
}

__global__ __launch_bounds__(1024) void k_scan(
    const int* __restrict__ counts, int* __restrict__ offsets,
    int* __restrict__ cursor)
{
    __shared__ int part[1024];
    const int t = threadIdx.x;
    const int s0 = t * 16;
    const int s1 = (s0 + 16 < NN_NODES) ? s0 + 16 : NN_NODES;
    int s = 0;
    for (int i = s0; i < s1; ++i) s += counts[i];
    part[t] = s;
    __syncthreads();
    for (int off = 1; off < 1024; off <<= 1) {
        int v = part[t];
        if (t >= off) v += part[t - off];
        __syncthreads();
        part[t] = v;
        __syncthreads();
    }
    int run = t ? part[t - 1] : 0;
    for (int i = s0; i < s1; ++i) {
        offsets[i] = run; cursor[i] = run; run += counts[i];
    }
}

__global__ __launch_bounds__(1024) void k_binfill(
    const int* __restrict__ senders, int* __restrict__ cursor,
    int* __restrict__ order, int E)
{
    const int e = blockIdx.x * 1024 + threadIdx.x;
    if (e < E) {
        const int p = atomicAdd(&cursor[senders[e]], 1);
        order[p] = e;
    }
}

// =====================================================================
// k_env: w = (x*m) @ WenvT via MFMA. 128 edges/block. Output bf16
// interleaved rows (w0[l],w1[l]) pairs, written to scratch (out_v region).
// =====================================================================
__global__ __launch_bounds__(512) void k_env(
    const float* __restrict__ x, const float* __restrict__ m,
    const char* __restrict__ wsb, char* __restrict__ wout, int E)
{
    __shared__ char lds[65536];  // [0,32K): xm swz / results; [32K,64K): WenvT
    const int tid = threadIdx.x;

    {   // stage WenvT (pre-swizzled): 64B/thread
        const int4* src = (const int4*)(wsb + WS_WE);
        int4* dst = (int4*)(lds + 32768);
        #pragma unroll
        for (int j = 0; j < 4; ++j) dst[tid * 4 + j] = src[tid * 4 + j];
    }

    const int eb = blockIdx.x * 128;
    {   // xm tile: 4 threads/edge
        const int el = tid >> 2, q = tid & 3;
        const int e = eb + el;
        if (e < E) {
            const float mv = m[e];
            const float4* xp = (const float4*)&x[(size_t)e * 128 + q * 32];
            #pragma unroll
            for (int j = 0; j < 4; ++j) {
                float4 A = xp[2 * j], B = xp[2 * j + 1];
                int4 w;
                w.x = packbf(A.x * mv, A.y * mv); w.y = packbf(A.z * mv, A.w * mv);
                w.z = packbf(B.x * mv, B.y * mv); w.w = packbf(B.z * mv, B.w * mv);
                *(int4*)(lds + el * 256 + swz(el, q * 64 + j * 16)) = w;
            }
        } else {
            const int4 z = {0, 0, 0, 0};
            #pragma unroll
            for (int j = 0; j < 4; ++j)
                *(int4*)(lds + el * 256 + swz(el, q * 64 + j * 16)) = z;
        }
    }
    __syncthreads();

    const int l = tid & 63, wid = tid >> 6;
    const int wm = wid & 3, wn = wid >> 2;
    const int m0 = wm * 32, n0 = wn * 64;
    const int lr = l & 15, lg = l >> 4;

    f32x4 acc[2][4];
    #pragma unroll
    for (int a = 0; a < 2; ++a)
        #pragma unroll
        for (int b = 0; b < 4; ++b) acc[a][b] = (f32x4){0.f, 0.f, 0.f, 0.f};

    #pragma unroll
    for (int kk = 0; kk < 4; ++kk) {
        const int kb = kk * 64 + lg * 16;
        bf16x8 a0 = *(const bf16x8*)(lds + (m0 + lr) * 256      + swz(m0 + lr, kb));
        bf16x8 a1 = *(const bf16x8*)(lds + (m0 + 16 + lr) * 256 + swz(m0 + 16 + lr, kb));
        #pragma unroll
        for (int nt = 0; nt < 4; ++nt) {
            const int row = n0 + nt * 16 + lr;
            bf16x8 bb = *(const bf16x8*)(lds + 32768 + row * 256 + swz(row, kb));
            acc[0][nt] = __builtin_amdgcn_mfma_f32_16x16x32_bf16(a0, bb, acc[0][nt], 0, 0, 0);
            acc[1][nt] = __builtin_amdgcn_mfma_f32_16x16x32_bf16(a1, bb, acc[1][nt], 0, 0, 0);
        }
    }
    __syncthreads();

    // results -> lds[0:32K) linear [128 rows][256B], then coalesced copy-out
    #pragma unroll
    for (int mt = 0; mt < 2; ++mt)
        #pragma unroll
        for (int nt = 0; nt < 4; ++nt)
            #pragma unroll
            for (int r = 0; r < 4; ++r) {
                const int row = m0 + mt * 16 + lg * 4 + r;
                const int col = n0 + nt * 16 + lr;
                *(unsigned short*)(lds + row * 256 + col * 2) = bf16r(acc[mt][nt][r]);
            }
    __syncthreads();
    {
        const int4* s = (const int4*)lds;
        int4* d = (int4*)(wout + (size_t)eb * 256);
        #pragma unroll
        for (int j = 0; j < 4; ++j) d[tid * 4 + j] = s[tid * 4 + j];
    }
}

// =====================================================================
// k_gather: one wave per node; accumulate sorted edges' w rows; write
// node accumulators once (no atomics, no pre-zeroing needed).
// =====================================================================
__global__ __launch_bounds__(256) void k_gather(
    const char* __restrict__ wvb, const float* __restrict__ vectors,
    const float* __restrict__ m, const int* __restrict__ counts,
    const int* __restrict__ offsets, const int* __restrict__ order,
    float* __restrict__ node_cnt, float* __restrict__ node_s,
    float* __restrict__ node_v)
{
    const int l = threadIdx.x & 63, wid = threadIdx.x >> 6;
    const int n = blockIdx.x * 4 + wid;
    if (n >= NN_NODES) return;
    const int cnt = counts[n], base = offsets[n];

    float as = 0.f, a0 = 0.f, a1 = 0.f, a2 = 0.f, am = 0.f;
    for (int i = 0; i < cnt; ++i) {
        const int e = order[base + i];
        const unsigned int wv = *(const unsigned int*)(wvb + (size_t)e * 256 + l * 4);
        const float mm = m[e];
        const float vx = vectors[(size_t)e * 3 + 0];
        const float vy = vectors[(size_t)e * 3 + 1];
        const float vz = vectors[(size_t)e * 3 + 2];
        const float rn = 1.7320508075688772f / sqrtf(vx * vx + vy * vy + vz * vz);
        const float w0 = bflo(wv) * mm;
        const float c1 = bfhi(wv) * mm * rn;
        as += w0; am += mm;
        a0 += c1 * vx; a1 += c1 * vy; a2 += c1 * vz;
    }
    if (l == 0) node_cnt[n] = am;
    node_s[(size_t)n * 64 + l] = as;
    float* nv = &node_v[((size_t)n * 64 + l) * 3];
    nv[0] = a0; nv[1] = a1; nv[2] = a2;
}

// =====================================================================
// k_prep_vout: gather + s_a/s_b stash + V_in tile + MFMA V_out.
// Epilogue stages results in LDS (reusing vin space) for coalesced writes.
// =====================================================================
__global__ __launch_bounds__(512) void k_prep_vout(
    const float* __restrict__ V, const int* __restrict__ senders,
    const float* __restrict__ node_cnt, const float* __restrict__ node_s,
    const float* __restrict__ node_v, const char* __restrict__ wsb,
    float* __restrict__ out_x, float* __restrict__ out_v, int E)
{
    __shared__ char lds[49152 + 16384];   // vin[192][128]bf16 swz | WoutT 16K
    const int tid = threadIdx.x, l = tid & 63, wid = tid >> 6;

    {
        const int4* src = (const int4*)(wsb + WS_WO);
        int4 a = src[tid * 2], b = src[tid * 2 + 1];
        ((int4*)(lds + 49152))[tid * 2]     = a;
        ((int4*)(lds + 49152))[tid * 2 + 1] = b;
    }

    const int eb = blockIdx.x * 64;
    #pragma unroll 2
    for (int i = 0; i < 8; ++i) {
        const int el = wid * 8 + i;
        const int e  = eb + el;
        float Vs = 0.f, Vv0 = 0.f, Vv1 = 0.f, Vv2 = 0.f;
        float wYs = 0.f, wv0 = 0.f, wv1 = 0.f, wv2 = 0.f;
        if (e < E) {
            Vs = V[(size_t)e * 256 + l];
            const float* vp = &V[(size_t)e * 256 + 64 + l * 3];
            Vv0 = vp[0]; Vv1 = vp[1]; Vv2 = vp[2];
            const int sn = senders[e];
            const float rden = 1.0f / (node_cnt[sn] + 1e-5f);
            wYs = node_s[(size_t)sn * 64 + l] * rden;
            const float* nvp = &node_v[((size_t)sn * 64 + l) * 3];
            wv0 = nvp[0] * rden; wv1 = nvp[1] * rden; wv2 = nvp[2] * rden;
            unsigned short* sab = (unsigned short*)((char*)out_x + (size_t)e * 512);
            sab[l]      = bf16r(wYs * Vs);
            sab[64 + l] = bf16r((wv0 * Vv0 + wv1 * Vv1 + wv2 * Vv2) * 0.57735026918962576f);
        }
        const float vvk[3] = {Vv0, Vv1, Vv2};
        const float wvk[3] = {wv0, wv1, wv2};
        #pragma unroll
        for (int k = 0; k < 3; ++k) {
            const int row = el * 3 + k;
            *(unsigned short*)(lds + row * 256 + swz(row, l * 2))       = bf16r(wYs * vvk[k]);
            *(unsigned short*)(lds + row * 256 + swz(row, 128 + l * 2)) = bf16r(wvk[k] * Vs);
        }
    }
    __syncthreads();

    const int wm = wid & 3, wn = wid >> 2;
    const int m0 = wm * 48, n0 = wn * 32;
    const int lr = l & 15, lg = l >> 4;
    f32x4 acc[3][2];
    #pragma unroll
    for (int a = 0; a < 3; ++a)
        #pragma unroll
        for (int b = 0; b < 2; ++b) acc[a][b] = (f32x4){0.f, 0.f, 0.f, 0.f};

    #pragma unroll
    for (int kk = 0; kk < 4; ++kk) {
        const int kb = kk * 64 + lg * 16;
        bf16x8 a0 = *(const bf16x8*)(lds + (m0 + lr) * 256      + swz(m0 + lr, kb));
        bf16x8 a1 = *(const bf16x8*)(lds + (m0 + 16 + lr) * 256 + swz(m0 + 16 + lr, kb));
        bf16x8 a2 = *(const bf16x8*)(lds + (m0 + 32 + lr) * 256 + swz(m0 + 32 + lr, kb));
        bf16x8 b0 = *(const bf16x8*)(lds + 49152 + (n0 + lr) * 256      + swz(n0 + lr, kb));
        bf16x8 b1 = *(const bf16x8*)(lds + 49152 + (n0 + 16 + lr) * 256 + swz(n0 + 16 + lr, kb));
        acc[0][0] = __builtin_amdgcn_mfma_f32_16x16x32_bf16(a0, b0, acc[0][0], 0, 0, 0);
        acc[0][1] = __builtin_amdgcn_mfma_f32_16x16x32_bf16(a0, b1, acc[0][1], 0, 0, 0);
        acc[1][0] = __builtin_amdgcn_mfma_f32_16x16x32_bf16(a1, b0, acc[1][0], 0, 0, 0);
        acc[1][1] = __builtin_amdgcn_mfma_f32_16x16x32_bf16(a1, b1, acc[1][1], 0, 0, 0);
        acc[2][0] = __builtin_amdgcn_mfma_f32_16x16x32_bf16(a2, b0, acc[2][0], 0, 0, 0);
        acc[2][1] = __builtin_amdgcn_mfma_f32_16x16x32_bf16(a2, b1, acc[2][1], 0, 0, 0);
    }
    __syncthreads();   // all waves done reading vin -> reuse as f32 result tile

    // stage results: lds[el*768 + (o*3+kd)*4] = global layout for this block
    #pragma unroll
    for (int mt = 0; mt < 3; ++mt)
        #pragma unroll
        for (int nt = 0; nt < 2; ++nt)
            #pragma unroll
            for (int r = 0; r < 4; ++r) {
                const int mm = m0 + mt * 16 + lg * 4 + r;
                const int el2 = mm / 3, kd = mm - el2 * 3;
                const int o = n0 + nt * 16 + lr;
                *(float*)(lds + el2 * 768 + (o * 3 + kd) * 4) = acc[mt][nt][r];
            }
    __syncthreads();
    if (eb + 64 <= E) {   // coalesced 48KB copy-out
        const int4* s = (const int4*)lds;
        int4* d = (int4*)(out_v + (size_t)eb * 192);
        #pragma unroll
        for (int j = 0; j < 6; ++j) d[tid * 6 + j] = s[tid * 6 + j];
    } else {
        for (int idx = tid; idx < 64 * 192; idx += 512) {
            const int el2 = idx / 192;
            if (eb + el2 < E)
                out_v[(size_t)(eb + el2) * 192 + (idx % 192)] = *(float*)(lds + idx * 4);
        }
    }
}

// =====================================================================
// k_mlp: fused MLP via MFMA, 128 edges/block, 64KB LDS (2 blocks/CU).
// B-fragments (W1T/W2T/W3T) read directly from global (L2-hot).
// =====================================================================
__global__ __launch_bounds__(512, 4) void k_mlp(
    const float* __restrict__ x, const float* __restrict__ m,
    const float* __restrict__ ug, const char* __restrict__ wsb,
    float* __restrict__ out_x, float inv_c, int E)
{
    __shared__ char lds[65536];  // xcat[128][512B] swz; later h [0:32K), g [32K:64K)
    const int tid = threadIdx.x;

    const int eb = blockIdx.x * 128;
    {   // xcat prep: 4 threads per edge
        const int el = tid >> 2, q = tid & 3;
        const int e  = eb + el;
        if (e < E) {
            const float mv = m[e];
            const float4* xp = (const float4*)&x[(size_t)e * 128 + q * 32];
            #pragma unroll
            for (int j = 0; j < 4; ++j) {
                float4 A = xp[2 * j], B = xp[2 * j + 1];
                int4 w;
                w.x = packbf(A.x * mv, A.y * mv); w.y = packbf(A.z * mv, A.w * mv);
                w.z = packbf(B.x * mv, B.y * mv); w.w = packbf(B.z * mv, B.w * mv);
                *(int4*)(lds + el * 512 + swz(el, q * 64 + j * 16)) = w;
            }
            const int4* sp = (const int4*)((const char*)out_x + (size_t)e * 512 + q * 64);
            #pragma unroll
            for (int j = 0; j < 4; ++j) {
                int4 v = sp[j];
                *(int4*)(lds + el * 512 + swz(el, 256 + q * 64 + j * 16)) = v;
            }
        } else {
            const int4 z = {0, 0, 0, 0};
            #pragma unroll
            for (int j = 0; j < 4; ++j) {
                *(int4*)(lds + el * 512 + swz(el, q * 64 + j * 16)) = z;
                *(int4*)(lds + el * 512 + swz(el, 256 + q * 64 + j * 16)) = z;
            }
        }
    }
    __syncthreads();

    const int l = tid & 63, wid = tid >> 6;
    const int wm = wid >> 1, wn = wid & 1;
    const int m0 = wm * 32, n0 = wn * 64;
    const int lr = l & 15, lg = l >> 4;

    const char* w1g = wsb + WS_W1;
    const char* w2g = wsb + WS_W2;
    const char* w3g = wsb + WS_W3;

    // ---- stage 1: xcat[128x256] @ W1T (K=256), B direct from global ----
    f32x4 acc[2][4];
    #pragma unroll
    for (int a = 0; a < 2; ++a)
        #pragma unroll
        for (int b = 0; b < 4; ++b) acc[a][b] = (f32x4){0.f, 0.f, 0.f, 0.f};
    #pragma unroll 2
    for (int kk = 0; kk < 8; ++kk) {
        const int kb = kk * 64 + lg * 16;
        bf16x8 a0 = *(const bf16x8*)(lds + (m0 + lr) * 512      + swz(m0 + lr, kb));
        bf16x8 a1 = *(const bf16x8*)(lds + (m0 + 16 + lr) * 512 + swz(m0 + 16 + lr, kb));
        #pragma unroll
        for (int nt = 0; nt < 4; ++nt) {
            const int row = n0 + nt * 16 + lr;
            bf16x8 bb = *(const bf16x8*)(w1g + row * 512 + kb);
            acc[0][nt] = __builtin_amdgcn_mfma_f32_16x16x32_bf16(a0, bb, acc[0][nt], 0, 0, 0);
            acc[1][nt] = __builtin_amdgcn_mfma_f32_16x16x32_bf16(a1, bb, acc[1][nt], 0, 0, 0);
        }
    }
    __syncthreads();   // all waves done with xcat

    // write h (bf16, swizzled, stride 256B) into lds[0:32K)
    #pragma unroll
    for (int mt = 0; mt < 2; ++mt)
        #pragma unroll
        for (int nt = 0; nt < 4; ++nt)
            #pragma unroll
            for (int r = 0; r < 4; ++r) {
                const int row = m0 + mt * 16 + lg * 4 + r;
                const int col = n0 + nt * 16 + lr;
                *(unsigned short*)(lds + row * 256 + swz(row, col * 2)) =
                    bf16r(nsilu(acc[mt][nt][r], inv_c));
            }
    __syncthreads();

    // ---- stage 2: h @ W2T (K=128) ----
    f32x4 acc2[2][4];
    #pragma unroll
    for (int a = 0; a < 2; ++a)
        #pragma unroll
        for (int b = 0; b < 4; ++b) acc2[a][b] = (f32x4){0.f, 0.f, 0.f, 0.f};
    #pragma unroll
    for (int kk = 0; kk < 4; ++kk) {
        const int kb = kk * 64 + lg * 16;
        bf16x8 a0 = *(const bf16x8*)(lds + (m0 + lr) * 256      + swz(m0 + lr, kb));
        bf16x8 a1 = *(const bf16x8*)(lds + (m0 + 16 + lr) * 256 + swz(m0 + 16 + lr, kb));
        #pragma unroll
        for (int nt = 0; nt < 4; ++nt) {
            const int row = n0 + nt * 16 + lr;
            bf16x8 bb = *(const bf16x8*)(w2g + row * 256 + kb);
            acc2[0][nt] = __builtin_amdgcn_mfma_f32_16x16x32_bf16(a0, bb, acc2[0][nt], 0, 0, 0);
            acc2[1][nt] = __builtin_amdgcn_mfma_f32_16x16x32_bf16(a1, bb, acc2[1][nt], 0, 0, 0);
        }
    }
    // write g -> lds[32K:64K) (disjoint from h region; no barrier needed first)
    #pragma unroll
    for (int mt = 0; mt < 2; ++mt)
        #pragma unroll
        for (int nt = 0; nt < 4; ++nt)
            #pragma unroll
            for (int r = 0; r < 4; ++r) {
                const int row = m0 + mt * 16 + lg * 4 + r;
                const int col = n0 + nt * 16 + lr;
                *(unsigned short*)(lds + 32768 + row * 256 + swz(row, col * 2)) =
                    bf16r(nsilu(acc2[mt][nt][r], inv_c));
            }
    __syncthreads();

    // ---- stage 3: g @ W3T (K=128), scale by u, store ----
    f32x4 acc3[2][4];
    #pragma unroll
    for (int a = 0; a < 2; ++a)
        #pragma unroll
        for (int b = 0; b < 4; ++b) acc3[a][b] = (f32x4){0.f, 0.f, 0.f, 0.f};
    #pragma unroll
    for (int kk = 0; kk < 4; ++kk) {
        const int kb = kk * 64 + lg * 16;
        bf16x8 a0 = *(const bf16x8*)(lds + 32768 + (m0 + lr) * 256      + swz(m0 + lr, kb));
        bf16x8 a1 = *(const bf16x8*)(lds + 32768 + (m0 + 16 + lr) * 256 + swz(m0 + 16 + lr, kb));
        #pragma unroll
        for (int nt = 0; nt < 4; ++nt) {
            const int row = n0 + nt * 16 + lr;
            bf16x8 bb = *(const bf16x8*)(w3g + row * 256 + kb);
            acc3[0][nt] = __builtin_amdgcn_mfma_f32_16x16x32_bf16(a0, bb, acc3[0][nt], 0, 0, 0);
            acc3[1][nt] = __builtin_amdgcn_mfma_f32_16x16x32_bf16(a1, bb, acc3[1][nt], 0, 0, 0);
        }
    }
    #pragma unroll
    for (int mt = 0; mt < 2; ++mt)
        #pragma unroll
        for (int r = 0; r < 4; ++r) {
            const int e = eb + m0 + mt * 16 + lg * 4 + r;
            if (e < E) {
                const float uu = ug[e];
                #pragma unroll
                for (int nt = 0; nt < 4; ++nt)
                    out_x[(size_t)e * 128 + n0 + nt * 16 + lr] = uu * acc3[mt][nt][r];
            }
        }
}

// =====================================================================
extern "C" void kernel_launch(void* const* d_in, const int* in_sizes, int n_in,
                              void* d_out, int out_size, void* d_ws, size_t ws_size,
                              hipStream_t stream) {
    const float* vectors = (const float*)d_in[0];
    const float* x       = (const float*)d_in[1];
    const float* V       = (const float*)d_in[2];
    const float* u       = (const float*)d_in[3];
    const float* m       = (const float*)d_in[4];
    const float* W_env   = (const float*)d_in[5];
    const float* W1      = (const float*)d_in[6];
    const float* W2      = (const float*)d_in[7];
    const float* W3      = (const float*)d_in[8];
    const float* W_out   = (const float*)d_in[9];
    const int*   senders = (const int*)d_in[10];

    const int E = in_sizes[4];   // 256000

    char*  wsb      = (char*)d_ws;
    float* node_cnt = (float*)d_ws;
    float* node_s   = node_cnt + NN_NODES;
    float* node_v   = node_s + (size_t)NN_NODES * 64;
    int* counts  = (int*)(wsb + WS_COUNTS);
    int* offsets = (int*)(wsb + WS_OFFSETS);
    int* cursor  = (int*)(wsb + WS_CURSOR);
    int* order   = (int*)(wsb + WS_ORDER);

    float* out_x = (float*)d_out;
    float* out_v = out_x + (size_t)E * 128;
    char*  wvb   = (char*)out_v;   // w scratch lives in out_v region

    k_wprep<<<128, 256, 0, stream>>>(W1, W2, W3, W_out, W_env, wsb);
    k_hist<<<(E + 1023) / 1024, 1024, 0, stream>>>(senders, counts, E);
    k_scan<<<1, 1024, 0, stream>>>(counts, offsets, cursor);
    k_binfill<<<(E + 1023) / 1024, 1024, 0, stream>>>(senders, cursor, order, E);
    k_env<<<(E + 127) / 128, 512, 0, stream>>>(x, m, wsb, wvb, E);
    k_gather<<<(NN_NODES + 3) / 4, 256, 0, stream>>>(wvb, vectors, m, counts,
                                                     offsets, order,
                                                     node_cnt, node_s, node_v);
    k_prep_vout<<<(E + 63) / 64, 512, 0, stream>>>(V, senders, node_cnt, node_s,
                                                   node_v, wsb, out_x, out_v, E);
    k_mlp<<<(E + 127) / 128, 512, 0, stream>>>(x, m, u, wsb, out_x, INV_SILU_C, E);
}

// Round 6
// 455.336 us; speedup vs baseline: 1.1144x; 1.1144x over previous
//
#include <hip/hip_runtime.h>
#include <math.h>

typedef short bf16x8 __attribute__((ext_vector_type(8)));
typedef float f32x4 __attribute__((ext_vector_type(4)));

#define S128 0.08838834764831845f   /* 1/sqrt(128) */
#define S256I 0.0625f               /* 1/sqrt(256) */
#define NN_NODES 16000

// ws layout (bytes)
#define WS_COUNTS   16448000            /* int[16000] (node arrays occupy [0,16448000)) */
#define WS_OFFSETS  (WS_COUNTS + 64000)
#define WS_CURSOR   (WS_OFFSETS + 64000)
#define WS_ORDER    (WS_CURSOR + 64000) /* int[256000] */
#define WS_W1 (WS_ORDER + 1024000)      /* W1T [128][256] bf16 unswizzled */
#define WS_W2 (WS_W1 + 65536)           /* W2T [128][128] bf16 unswizzled */
#define WS_W3 (WS_W2 + 32768)           /* W3T [128][128] bf16 unswizzled */
#define WS_WO (WS_W3 + 32768)           /* WoutT [64][128] bf16 swizzled (LDS-staged) */
#define WS_WE (WS_WO + 16384)           /* WenvT [128][128] bf16 unswizzled (reg-loaded) */

// ---- host-side constant: SILU_C exactly as the reference computes it ----
static float compute_inv_silu_c() {
    double sum = 0.0, prev = 0.0;
    const double dz = 24.0 / 100000.0;
    for (int i = 0; i <= 100000; ++i) {
        double z = -12.0 + dz * (double)i;
        double pdf = exp(-0.5 * z * z) * 0.3989422804014327;
        double s = z / (1.0 + exp(-z));
        double f = s * s * pdf;
        if (i) sum += 0.5 * (prev + f) * dz;
        prev = f;
    }
    return (float)(1.0 / sqrt(sum));
}
static const float INV_SILU_C = compute_inv_silu_c();

// ---- device helpers ----
__device__ __forceinline__ unsigned int packbf(float a, float b) {
    union { float f; unsigned int u; } ca, cb;
    ca.f = a; cb.f = b;
    unsigned int ua = ca.u + (0x7fffu + ((ca.u >> 16) & 1u));
    unsigned int ub = cb.u + (0x7fffu + ((cb.u >> 16) & 1u));
    return (ua >> 16) | (ub & 0xffff0000u);
}
__device__ __forceinline__ unsigned short bf16r(float v) {
    union { float f; unsigned int u; } c; c.f = v;
    return (unsigned short)((c.u + (0x7fffu + ((c.u >> 16) & 1u))) >> 16);
}
__device__ __forceinline__ float bflo(unsigned int u) { return __uint_as_float(u << 16); }
__device__ __forceinline__ float bfhi(unsigned int u) { return __uint_as_float(u & 0xffff0000u); }
__device__ __forceinline__ int swz(int row, int b) { return b ^ ((row & 7) << 4); }
__device__ __forceinline__ float nsilu(float v, float ic) {
    return v / (1.0f + __expf(-v)) * ic;
}

// =====================================================================
// k_wprep: bf16-quantize + transpose weights into ws; zero counts[].
// W1/W2/W3/Wenv unswizzled (loaded to registers). Wout swizzled (LDS).
// =====================================================================
__global__ __launch_bounds__(256) void k_wprep(
    const float* __restrict__ W1, const float* __restrict__ W2,
    const float* __restrict__ W3, const float* __restrict__ Wout,
    const float* __restrict__ Wenv, char* __restrict__ wsb)
{
    const int t = blockIdx.x * 256 + threadIdx.x;   // 32768 threads
    if (t < NN_NODES) ((int*)(wsb + WS_COUNTS))[t] = 0;
    if (t < 32768) {  // W1T[128][256]
        int n = t & 127, k = t >> 7;
        *(unsigned short*)(wsb + WS_W1 + n * 512 + k * 2) =
            bf16r(W1[k * 128 + n] * S256I);
    }
    if (t < 16384) {  // W2T, W3T [128][128]
        int n = t & 127, k = t >> 7;
        *(unsigned short*)(wsb + WS_W2 + n * 256 + k * 2) =
            bf16r(W2[k * 128 + n] * S128);
        *(unsigned short*)(wsb + WS_W3 + n * 256 + k * 2) =
            bf16r(W3[k * 128 + n] * S128);
    }
    if (t < 16384) {  // WenvT[128][128], interleaved row perm (w0/w1 pairs)
        int j = t & 127, k = t >> 7;
        int c = (j & 1) ? 64 + (j >> 1) : (j >> 1);
        *(unsigned short*)(wsb + WS_WE + j * 256 + k * 2) =
            bf16r(Wenv[k * 128 + c] * S128);
    }
    if (t < 8192) {   // WoutT[64][128] swizzled
        int o = t & 63, uu = t >> 6;
        *(unsigned short*)(wsb + WS_WO + o * 256 + ((uu * 2) ^ ((o & 7) << 4))) =
            bf16r(Wout[uu * 64 + o] * S128);
    }
}

// =====================================================================
// sort-by-sender chain
// =====================================================================
__global__ __launch_bounds__(1024) void k_hist(
    const int* __restrict__ senders, int* __restrict__ counts, int E)
{
    const int e = blockIdx.x * 1024 + threadIdx.x;
    if (e < E) atomicAdd(&counts[senders[e]], 1);
}

__global__ __launch_bounds__(1024) void k_scan(
    const int* __restrict__ counts, int* __restrict__ offsets,
    int* __restrict__ cursor)
{
    __shared__ int part[1024];
    const int t = threadIdx.x;
    const int s0 = t * 16;
    const int s1 = (s0 + 16 < NN_NODES) ? s0 + 16 : NN_NODES;
    int s = 0;
    for (int i = s0; i < s1; ++i) s += counts[i];
    part[t] = s;
    __syncthreads();
    for (int off = 1; off < 1024; off <<= 1) {
        int v = part[t];
        if (t >= off) v += part[t - off];
        __syncthreads();
        part[t] = v;
        __syncthreads();
    }
    int run = t ? part[t - 1] : 0;
    for (int i = s0; i < s1; ++i) {
        offsets[i] = run; cursor[i] = run; run += counts[i];
    }
}

__global__ __launch_bounds__(1024) void k_binfill(
    const int* __restrict__ senders, int* __restrict__ cursor,
    int* __restrict__ order, int E)
{
    const int e = blockIdx.x * 1024 + threadIdx.x;
    if (e < E) {
        const int p = atomicAdd(&cursor[senders[e]], 1);
        order[p] = e;
    }
}

// =====================================================================
// k_env: w = (x*m) @ WenvT via MFMA. 128 edges/block, 32KB LDS.
// WenvT B-fragments held in registers (each wave owns 16 output cols).
// =====================================================================
__global__ __launch_bounds__(512) void k_env(
    const float* __restrict__ x, const float* __restrict__ m,
    const char* __restrict__ wsb, char* __restrict__ wout, int E)
{
    __shared__ char lds[32768];  // xm [128][256B] swz; reused for bf16 results
    const int tid = threadIdx.x, l = tid & 63, wid = tid >> 6;
    const int lr = l & 15, lg = l >> 4;
    const int n0 = wid * 16;

    // WenvT fragments for this wave's 16 columns (loop-invariant)
    bf16x8 B[4];
    #pragma unroll
    for (int kk = 0; kk < 4; ++kk)
        B[kk] = *(const bf16x8*)(wsb + WS_WE + (n0 + lr) * 256 + kk * 64 + lg * 16);

    const int eb = blockIdx.x * 128;
    {   // xm tile: 4 threads/edge
        const int el = tid >> 2, q = tid & 3;
        const int e = eb + el;
        if (e < E) {
            const float mv = m[e];
            const float4* xp = (const float4*)&x[(size_t)e * 128 + q * 32];
            #pragma unroll
            for (int j = 0; j < 4; ++j) {
                float4 A = xp[2 * j], Bv = xp[2 * j + 1];
                int4 w;
                w.x = packbf(A.x * mv, A.y * mv); w.y = packbf(A.z * mv, A.w * mv);
                w.z = packbf(Bv.x * mv, Bv.y * mv); w.w = packbf(Bv.z * mv, Bv.w * mv);
                *(int4*)(lds + el * 256 + swz(el, q * 64 + j * 16)) = w;
            }
        } else {
            const int4 z = {0, 0, 0, 0};
            #pragma unroll
            for (int j = 0; j < 4; ++j)
                *(int4*)(lds + el * 256 + swz(el, q * 64 + j * 16)) = z;
        }
    }
    __syncthreads();

    f32x4 acc[8];
    #pragma unroll
    for (int a = 0; a < 8; ++a) acc[a] = (f32x4){0.f, 0.f, 0.f, 0.f};

    #pragma unroll
    for (int kk = 0; kk < 4; ++kk) {
        const int kb = kk * 64 + lg * 16;
        #pragma unroll
        for (int mt = 0; mt < 8; ++mt) {
            const int row = mt * 16 + lr;
            bf16x8 a = *(const bf16x8*)(lds + row * 256 + swz(row, kb));
            acc[mt] = __builtin_amdgcn_mfma_f32_16x16x32_bf16(a, B[kk], acc[mt], 0, 0, 0);
        }
    }
    __syncthreads();   // all A-reads done; reuse buffer for results

    #pragma unroll
    for (int mt = 0; mt < 8; ++mt)
        #pragma unroll
        for (int r = 0; r < 4; ++r) {
            const int row = mt * 16 + lg * 4 + r;
            *(unsigned short*)(lds + row * 256 + (((n0 + lr) * 2) ^ ((row & 7) << 4))) =
                bf16r(acc[mt][r]);
        }
    __syncthreads();

    {   // coalesced copy-out, unswizzling
        const int el = tid >> 2, q = tid & 3;
        const int e = eb + el;
        if (e < E) {
            int4* d = (int4*)(wout + (size_t)e * 256 + q * 64);
            #pragma unroll
            for (int j = 0; j < 4; ++j)
                d[j] = *(int4*)(lds + el * 256 + ((q * 64 + j * 16) ^ ((el & 7) << 4)));
        }
    }
}

// =====================================================================
// k_gather: one wave per node; accumulate sorted edges' w rows; write
// node accumulators once (no atomics).
// =====================================================================
__global__ __launch_bounds__(256) void k_gather(
    const char* __restrict__ wvb, const float* __restrict__ vectors,
    const float* __restrict__ m, const int* __restrict__ counts,
    const int* __restrict__ offsets, const int* __restrict__ order,
    float* __restrict__ node_cnt, float* __restrict__ node_s,
    float* __restrict__ node_v)
{
    const int l = threadIdx.x & 63, wid = threadIdx.x >> 6;
    const int n = blockIdx.x * 4 + wid;
    if (n >= NN_NODES) return;
    const int cnt = counts[n], base = offsets[n];

    float as = 0.f, a0 = 0.f, a1 = 0.f, a2 = 0.f, am = 0.f;
    for (int i = 0; i < cnt; ++i) {
        const int e = order[base + i];
        const unsigned int wv = *(const unsigned int*)(wvb + (size_t)e * 256 + l * 4);
        const float mm = m[e];
        const float vx = vectors[(size_t)e * 3 + 0];
        const float vy = vectors[(size_t)e * 3 + 1];
        const float vz = vectors[(size_t)e * 3 + 2];
        const float rn = 1.7320508075688772f / sqrtf(vx * vx + vy * vy + vz * vz);
        const float w0 = bflo(wv) * mm;
        const float c1 = bfhi(wv) * mm * rn;
        as += w0; am += mm;
        a0 += c1 * vx; a1 += c1 * vy; a2 += c1 * vz;
    }
    if (l == 0) node_cnt[n] = am;
    node_s[(size_t)n * 64 + l] = as;
    float* nv = &node_v[((size_t)n * 64 + l) * 3];
    nv[0] = a0; nv[1] = a1; nv[2] = a2;
}

// =====================================================================
// k_prep_vout: gather + s_a/s_b stash + V_in tile + MFMA V_out,
// LDS-staged coalesced writes.
// =====================================================================
__global__ __launch_bounds__(512) void k_prep_vout(
    const float* __restrict__ V, const int* __restrict__ senders,
    const float* __restrict__ node_cnt, const float* __restrict__ node_s,
    const float* __restrict__ node_v, const char* __restrict__ wsb,
    float* __restrict__ out_x, float* __restrict__ out_v, int E)
{
    __shared__ char lds[49152 + 16384];   // vin[192][128]bf16 swz | WoutT 16K
    const int tid = threadIdx.x, l = tid & 63, wid = tid >> 6;

    {
        const int4* src = (const int4*)(wsb + WS_WO);
        int4 a = src[tid * 2], b = src[tid * 2 + 1];
        ((int4*)(lds + 49152))[tid * 2]     = a;
        ((int4*)(lds + 49152))[tid * 2 + 1] = b;
    }

    const int eb = blockIdx.x * 64;
    #pragma unroll 2
    for (int i = 0; i < 8; ++i) {
        const int el = wid * 8 + i;
        const int e  = eb + el;
        float Vs = 0.f, Vv0 = 0.f, Vv1 = 0.f, Vv2 = 0.f;
        float wYs = 0.f, wv0 = 0.f, wv1 = 0.f, wv2 = 0.f;
        if (e < E) {
            Vs = V[(size_t)e * 256 + l];
            const float* vp = &V[(size_t)e * 256 + 64 + l * 3];
            Vv0 = vp[0]; Vv1 = vp[1]; Vv2 = vp[2];
            const int sn = senders[e];
            const float rden = 1.0f / (node_cnt[sn] + 1e-5f);
            wYs = node_s[(size_t)sn * 64 + l] * rden;
            const float* nvp = &node_v[((size_t)sn * 64 + l) * 3];
            wv0 = nvp[0] * rden; wv1 = nvp[1] * rden; wv2 = nvp[2] * rden;
            unsigned short* sab = (unsigned short*)((char*)out_x + (size_t)e * 512);
            sab[l]      = bf16r(wYs * Vs);
            sab[64 + l] = bf16r((wv0 * Vv0 + wv1 * Vv1 + wv2 * Vv2) * 0.57735026918962576f);
        }
        const float vvk[3] = {Vv0, Vv1, Vv2};
        const float wvk[3] = {wv0, wv1, wv2};
        #pragma unroll
        for (int k = 0; k < 3; ++k) {
            const int row = el * 3 + k;
            *(unsigned short*)(lds + row * 256 + swz(row, l * 2))       = bf16r(wYs * vvk[k]);
            *(unsigned short*)(lds + row * 256 + swz(row, 128 + l * 2)) = bf16r(wvk[k] * Vs);
        }
    }
    __syncthreads();

    const int wm = wid & 3, wn = wid >> 2;
    const int m0 = wm * 48, n0 = wn * 32;
    const int lr = l & 15, lg = l >> 4;
    f32x4 acc[3][2];
    #pragma unroll
    for (int a = 0; a < 3; ++a)
        #pragma unroll
        for (int b = 0; b < 2; ++b) acc[a][b] = (f32x4){0.f, 0.f, 0.f, 0.f};

    #pragma unroll
    for (int kk = 0; kk < 4; ++kk) {
        const int kb = kk * 64 + lg * 16;
        bf16x8 a0 = *(const bf16x8*)(lds + (m0 + lr) * 256      + swz(m0 + lr, kb));
        bf16x8 a1 = *(const bf16x8*)(lds + (m0 + 16 + lr) * 256 + swz(m0 + 16 + lr, kb));
        bf16x8 a2 = *(const bf16x8*)(lds + (m0 + 32 + lr) * 256 + swz(m0 + 32 + lr, kb));
        bf16x8 b0 = *(const bf16x8*)(lds + 49152 + (n0 + lr) * 256      + swz(n0 + lr, kb));
        bf16x8 b1 = *(const bf16x8*)(lds + 49152 + (n0 + 16 + lr) * 256 + swz(n0 + 16 + lr, kb));
        acc[0][0] = __builtin_amdgcn_mfma_f32_16x16x32_bf16(a0, b0, acc[0][0], 0, 0, 0);
        acc[0][1] = __builtin_amdgcn_mfma_f32_16x16x32_bf16(a0, b1, acc[0][1], 0, 0, 0);
        acc[1][0] = __builtin_amdgcn_mfma_f32_16x16x32_bf16(a1, b0, acc[1][0], 0, 0, 0);
        acc[1][1] = __builtin_amdgcn_mfma_f32_16x16x32_bf16(a1, b1, acc[1][1], 0, 0, 0);
        acc[2][0] = __builtin_amdgcn_mfma_f32_16x16x32_bf16(a2, b0, acc[2][0], 0, 0, 0);
        acc[2][1] = __builtin_amdgcn_mfma_f32_16x16x32_bf16(a2, b1, acc[2][1], 0, 0, 0);
    }
    __syncthreads();

    #pragma unroll
    for (int mt = 0; mt < 3; ++mt)
        #pragma unroll
        for (int nt = 0; nt < 2; ++nt)
            #pragma unroll
            for (int r = 0; r < 4; ++r) {
                const int mm = m0 + mt * 16 + lg * 4 + r;
                const int el2 = mm / 3, kd = mm - el2 * 3;
                const int o = n0 + nt * 16 + lr;
                *(float*)(lds + el2 * 768 + (o * 3 + kd) * 4) = acc[mt][nt][r];
            }
    __syncthreads();
    if (eb + 64 <= E) {
        const int4* s = (const int4*)lds;
        int4* d = (int4*)(out_v + (size_t)eb * 192);
        #pragma unroll
        for (int j = 0; j < 6; ++j) d[tid * 6 + j] = s[tid * 6 + j];
    } else {
        for (int idx = tid; idx < 64 * 192; idx += 512) {
            const int el2 = idx / 192;
            if (eb + el2 < E)
                out_v[(size_t)(eb + el2) * 192 + (idx % 192)] = *(float*)(lds + idx * 4);
        }
    }
}

// =====================================================================
// k_mlp: fused MLP via MFMA. 64 edges/block, 48KB LDS.
// All weight B-fragments in registers (wave owns 16 output cols).
// =====================================================================
__global__ __launch_bounds__(512, 4) void k_mlp(
    const float* __restrict__ x, const float* __restrict__ m,
    const float* __restrict__ ug, const char* __restrict__ wsb,
    float* __restrict__ out_x, float inv_c, int E)
{
    __shared__ char lds[49152];  // [0,32K): xcat swz -> g -> f32 out; [32K,48K): h
    const int tid = threadIdx.x, l = tid & 63, wid = tid >> 6;
    const int lr = l & 15, lg = l >> 4;
    const int n0 = wid * 16;
    const int eb = blockIdx.x * 64;

    // W1T fragments for this wave's 16 cols (K=256)
    bf16x8 B1[8];
    #pragma unroll
    for (int kk = 0; kk < 8; ++kk)
        B1[kk] = *(const bf16x8*)(wsb + WS_W1 + (n0 + lr) * 512 + kk * 64 + lg * 16);

    {   // xcat prep: 8 threads/edge
        const int el = tid >> 3, q = tid & 7;
        const int e = eb + el;
        if (e < E) {
            const float mv = m[e];
            const float4* xp = (const float4*)&x[(size_t)e * 128 + q * 16];
            float4 A = xp[0], Bv = xp[1], C = xp[2], D = xp[3];
            int4 w0, w1;
            w0.x = packbf(A.x * mv, A.y * mv);   w0.y = packbf(A.z * mv, A.w * mv);
            w0.z = packbf(Bv.x * mv, Bv.y * mv); w0.w = packbf(Bv.z * mv, Bv.w * mv);
            w1.x = packbf(C.x * mv, C.y * mv);   w1.y = packbf(C.z * mv, C.w * mv);
            w1.z = packbf(D.x * mv, D.y * mv);   w1.w = packbf(D.z * mv, D.w * mv);
            *(int4*)(lds + el * 512 + swz(el, q * 32))      = w0;
            *(int4*)(lds + el * 512 + swz(el, q * 32 + 16)) = w1;
            const int4* sp = (const int4*)((const char*)out_x + (size_t)e * 512 + q * 32);
            *(int4*)(lds + el * 512 + swz(el, 256 + q * 32))      = sp[0];
            *(int4*)(lds + el * 512 + swz(el, 256 + q * 32 + 16)) = sp[1];
        } else {
            const int4 z = {0, 0, 0, 0};
            *(int4*)(lds + el * 512 + swz(el, q * 32))            = z;
            *(int4*)(lds + el * 512 + swz(el, q * 32 + 16))       = z;
            *(int4*)(lds + el * 512 + swz(el, 256 + q * 32))      = z;
            *(int4*)(lds + el * 512 + swz(el, 256 + q * 32 + 16)) = z;
        }
    }
    __syncthreads();

    // ---- stage 1: xcat[64x256] @ W1T ----
    f32x4 a1[4];
    #pragma unroll
    for (int a = 0; a < 4; ++a) a1[a] = (f32x4){0.f, 0.f, 0.f, 0.f};
    #pragma unroll
    for (int kk = 0; kk < 8; ++kk) {
        const int kb = kk * 64 + lg * 16;
        #pragma unroll
        for (int mt = 0; mt < 4; ++mt) {
            const int row = mt * 16 + lr;
            bf16x8 a = *(const bf16x8*)(lds + row * 512 + swz(row, kb));
            a1[mt] = __builtin_amdgcn_mfma_f32_16x16x32_bf16(a, B1[kk], a1[mt], 0, 0, 0);
        }
    }

    // load W2T/W3T fragments (L2-hot; latency hidden by h-write + barrier)
    bf16x8 B2[4], B3[4];
    #pragma unroll
    for (int kk = 0; kk < 4; ++kk) {
        B2[kk] = *(const bf16x8*)(wsb + WS_W2 + (n0 + lr) * 256 + kk * 64 + lg * 16);
        B3[kk] = *(const bf16x8*)(wsb + WS_W3 + (n0 + lr) * 256 + kk * 64 + lg * 16);
    }

    // write h (bf16) to lds+32K (disjoint from xcat; no barrier needed before)
    #pragma unroll
    for (int mt = 0; mt < 4; ++mt)
        #pragma unroll
        for (int r = 0; r < 4; ++r) {
            const int row = mt * 16 + lg * 4 + r;
            *(unsigned short*)(lds + 32768 + row * 256 + swz(row, (n0 + lr) * 2)) =
                bf16r(nsilu(a1[mt][r], inv_c));
        }
    __syncthreads();

    // ---- stage 2: h @ W2T ----
    f32x4 a2[4];
    #pragma unroll
    for (int a = 0; a < 4; ++a) a2[a] = (f32x4){0.f, 0.f, 0.f, 0.f};
    #pragma unroll
    for (int kk = 0; kk < 4; ++kk) {
        const int kb = kk * 64 + lg * 16;
        #pragma unroll
        for (int mt = 0; mt < 4; ++mt) {
            const int row = mt * 16 + lr;
            bf16x8 a = *(const bf16x8*)(lds + 32768 + row * 256 + swz(row, kb));
            a2[mt] = __builtin_amdgcn_mfma_f32_16x16x32_bf16(a, B2[kk], a2[mt], 0, 0, 0);
        }
    }
    // write g (bf16) into lds[0:16K) — xcat reads all finished (h barrier)
    #pragma unroll
    for (int mt = 0; mt < 4; ++mt)
        #pragma unroll
        for (int r = 0; r < 4; ++r) {
            const int row = mt * 16 + lg * 4 + r;
            *(unsigned short*)(lds + row * 256 + swz(row, (n0 + lr) * 2)) =
                bf16r(nsilu(a2[mt][r], inv_c));
        }
    __syncthreads();

    // ---- stage 3: g @ W3T ----
    f32x4 a3[4];
    #pragma unroll
    for (int a = 0; a < 4; ++a) a3[a] = (f32x4){0.f, 0.f, 0.f, 0.f};
    #pragma unroll
    for (int kk = 0; kk < 4; ++kk) {
        const int kb = kk * 64 + lg * 16;
        #pragma unroll
        for (int mt = 0; mt < 4; ++mt) {
            const int row = mt * 16 + lr;
            bf16x8 a = *(const bf16x8*)(lds + row * 256 + swz(row, kb));
            a3[mt] = __builtin_amdgcn_mfma_f32_16x16x32_bf16(a, B3[kk], a3[mt], 0, 0, 0);
        }
    }
    __syncthreads();   // all g reads done; reuse lds[0:32K) for f32 results

    #pragma unroll
    for (int mt = 0; mt < 4; ++mt)
        #pragma unroll
        for (int r = 0; r < 4; ++r) {
            const int row = mt * 16 + lg * 4 + r;
            *(float*)(lds + row * 512 + (((n0 + lr) * 4) ^ ((row & 7) << 4))) = a3[mt][r];
        }
    __syncthreads();

    {   // coalesced copy-out with u scaling
        const int el = tid >> 3, q = tid & 7;
        const int e = eb + el;
        if (e < E) {
            const float uu = ug[e];
            #pragma unroll
            for (int j = 0; j < 4; ++j) {
                int4 v = *(int4*)(lds + el * 512 + ((q * 64 + j * 16) ^ ((el & 7) << 4)));
                float4 f;
                f.x = __int_as_float(v.x) * uu; f.y = __int_as_float(v.y) * uu;
                f.z = __int_as_float(v.z) * uu; f.w = __int_as_float(v.w) * uu;
                *(float4*)(&out_x[(size_t)e * 128 + q * 16 + j * 4]) = f;
            }
        }
    }
}

// =====================================================================
extern "C" void kernel_launch(void* const* d_in, const int* in_sizes, int n_in,
                              void* d_out, int out_size, void* d_ws, size_t ws_size,
                              hipStream_t stream) {
    const float* vectors = (const float*)d_in[0];
    const float* x       = (const float*)d_in[1];
    const float* V       = (const float*)d_in[2];
    const float* u       = (const float*)d_in[3];
    const float* m       = (const float*)d_in[4];
    const float* W_env   = (const float*)d_in[5];
    const float* W1      = (const float*)d_in[6];
    const float* W2      = (const float*)d_in[7];
    const float* W3      = (const float*)d_in[8];
    const float* W_out   = (const float*)d_in[9];
    const int*   senders = (const int*)d_in[10];

    const int E = in_sizes[4];   // 256000

    char*  wsb      = (char*)d_ws;
    float* node_cnt = (float*)d_ws;
    float* node_s   = node_cnt + NN_NODES;
    float* node_v   = node_s + (size_t)NN_NODES * 64;
    int* counts  = (int*)(wsb + WS_COUNTS);
    int* offsets = (int*)(wsb + WS_OFFSETS);
    int* cursor  = (int*)(wsb + WS_CURSOR);
    int* order   = (int*)(wsb + WS_ORDER);

    float* out_x = (float*)d_out;
    float* out_v = out_x + (size_t)E * 128;
    char*  wvb   = (char*)out_v;   // w scratch lives in out_v region

    k_wprep<<<128, 256, 0, stream>>>(W1, W2, W3, W_out, W_env, wsb);
    k_hist<<<(E + 1023) / 1024, 1024, 0, stream>>>(senders, counts, E);
    k_scan<<<1, 1024, 0, stream>>>(counts, offsets, cursor);
    k_binfill<<<(E + 1023) / 1024, 1024, 0, stream>>>(senders, cursor, order, E);
    k_env<<<(E + 127) / 128, 512, 0, stream>>>(x, m, wsb, wvb, E);
    k_gather<<<(NN_NODES + 3) / 4, 256, 0, stream>>>(wvb, vectors, m, counts,
                                                     offsets, order,
                                                     node_cnt, node_s, node_v);
    k_prep_vout<<<(E + 63) / 64, 512, 0, stream>>>(V, senders, node_cnt, node_s,
                                                   node_v, wsb, out_x, out_v, E);
    k_mlp<<<(E + 63) / 64, 512, 0, stream>>>(x, m, u, wsb, out_x, INV_SILU_C, E);
}

// Round 7
// 448.535 us; speedup vs baseline: 1.1313x; 1.0152x over previous
//
#include <hip/hip_runtime.h>
#include <math.h>

typedef short bf16x8 __attribute__((ext_vector_type(8)));
typedef float f32x4 __attribute__((ext_vector_type(4)));

#define S128 0.08838834764831845f   /* 1/sqrt(128) */
#define S256I 0.0625f               /* 1/sqrt(256) */
#define NN_NODES 16000

// ws layout (bytes)
#define WS_COUNTS   16448000            /* int[16000] (node arrays occupy [0,16448000)) */
#define WS_OFFSETS  (WS_COUNTS + 64000)
#define WS_CURSOR   (WS_OFFSETS + 64000)
#define WS_INV      (WS_CURSOR + 64000) /* int[256000]: e -> sorted pos */
#define WS_W1 (WS_INV + 1024000)        /* W1T [128][256] bf16 unswizzled */
#define WS_W2 (WS_W1 + 65536)           /* W2T [128][128] bf16 unswizzled */
#define WS_W3 (WS_W2 + 32768)           /* W3T [128][128] bf16 unswizzled */
#define WS_WO (WS_W3 + 32768)           /* WoutT [64][128] bf16 swizzled (LDS-staged) */
#define WS_WE (WS_WO + 16384)           /* WenvT [128][128] bf16 unswizzled (reg-loaded) */
#define WS_VECM (WS_WE + 32768)         /* float4[256000]: sorted (vx,vy,vz,m) */
#define WS_XMB  (WS_VECM + 4096000)     /* bf16 xm [E][128] linear, 65.5MB */

// ---- host-side constant: SILU_C exactly as the reference computes it ----
static float compute_inv_silu_c() {
    double sum = 0.0, prev = 0.0;
    const double dz = 24.0 / 100000.0;
    for (int i = 0; i <= 100000; ++i) {
        double z = -12.0 + dz * (double)i;
        double pdf = exp(-0.5 * z * z) * 0.3989422804014327;
        double s = z / (1.0 + exp(-z));
        double f = s * s * pdf;
        if (i) sum += 0.5 * (prev + f) * dz;
        prev = f;
    }
    return (float)(1.0 / sqrt(sum));
}
static const float INV_SILU_C = compute_inv_silu_c();

// ---- device helpers ----
__device__ __forceinline__ unsigned int packbf(float a, float b) {
    union { float f; unsigned int u; } ca, cb;
    ca.f = a; cb.f = b;
    unsigned int ua = ca.u + (0x7fffu + ((ca.u >> 16) & 1u));
    unsigned int ub = cb.u + (0x7fffu + ((cb.u >> 16) & 1u));
    return (ua >> 16) | (ub & 0xffff0000u);
}
__device__ __forceinline__ unsigned short bf16r(float v) {
    union { float f; unsigned int u; } c; c.f = v;
    return (unsigned short)((c.u + (0x7fffu + ((c.u >> 16) & 1u))) >> 16);
}
__device__ __forceinline__ float bflo(unsigned int u) { return __uint_as_float(u << 16); }
__device__ __forceinline__ float bfhi(unsigned int u) { return __uint_as_float(u & 0xffff0000u); }
__device__ __forceinline__ int swz(int row, int b) { return b ^ ((row & 7) << 4); }
__device__ __forceinline__ float nsilu(float v, float ic) {
    return v / (1.0f + __expf(-v)) * ic;
}

// =====================================================================
// k_wprep: bf16-quantize + transpose weights into ws; zero counts[].
// =====================================================================
__global__ __launch_bounds__(256) void k_wprep(
    const float* __restrict__ W1, const float* __restrict__ W2,
    const float* __restrict__ W3, const float* __restrict__ Wout,
    const float* __restrict__ Wenv, char* __restrict__ wsb)
{
    const int t = blockIdx.x * 256 + threadIdx.x;   // 32768 threads
    if (t < NN_NODES) ((int*)(wsb + WS_COUNTS))[t] = 0;
    if (t < 32768) {  // W1T[128][256]
        int n = t & 127, k = t >> 7;
        *(unsigned short*)(wsb + WS_W1 + n * 512 + k * 2) =
            bf16r(W1[k * 128 + n] * S256I);
    }
    if (t < 16384) {  // W2T, W3T [128][128]
        int n = t & 127, k = t >> 7;
        *(unsigned short*)(wsb + WS_W2 + n * 256 + k * 2) =
            bf16r(W2[k * 128 + n] * S128);
        *(unsigned short*)(wsb + WS_W3 + n * 256 + k * 2) =
            bf16r(W3[k * 128 + n] * S128);
    }
    if (t < 16384) {  // WenvT[128][128], interleaved row perm (w0/w1 pairs)
        int j = t & 127, k = t >> 7;
        int c = (j & 1) ? 64 + (j >> 1) : (j >> 1);
        *(unsigned short*)(wsb + WS_WE + j * 256 + k * 2) =
            bf16r(Wenv[k * 128 + c] * S128);
    }
    if (t < 8192) {   // WoutT[64][128] swizzled
        int o = t & 63, uu = t >> 6;
        *(unsigned short*)(wsb + WS_WO + o * 256 + ((uu * 2) ^ ((o & 7) << 4))) =
            bf16r(Wout[uu * 64 + o] * S128);
    }
}

// =====================================================================
// sort-by-sender chain
// =====================================================================
__global__ __launch_bounds__(1024) void k_hist(
    const int* __restrict__ senders, int* __restrict__ counts, int E)
{
    const int e = blockIdx.x * 1024 + threadIdx.x;
    if (e < E) atomicAdd(&counts[senders[e]], 1);
}

__global__ __launch_bounds__(1024) void k_scan(
    const int* __restrict__ counts, int* __restrict__ offsets,
    int* __restrict__ cursor)
{
    __shared__ int part[1024];
    const int t = threadIdx.x;
    const int s0 = t * 16;
    const int s1 = (s0 + 16 < NN_NODES) ? s0 + 16 : NN_NODES;
    int s = 0;
    for (int i = s0; i < s1; ++i) s += counts[i];
    part[t] = s;
    __syncthreads();
    for (int off = 1; off < 1024; off <<= 1) {
        int v = part[t];
        if (t >= off) v += part[t - off];
        __syncthreads();
        part[t] = v;
        __syncthreads();
    }
    int run = t ? part[t - 1] : 0;
    for (int i = s0; i < s1; ++i) {
        offsets[i] = run; cursor[i] = run; run += counts[i];
    }
}

// binfill: assign sorted position p per edge; emit inv[e]=p and
// vecm_sorted[p]=(vx,vy,vz,m) so the gather is fully streaming.
__global__ __launch_bounds__(1024) void k_binfill(
    const int* __restrict__ senders, const float* __restrict__ vectors,
    const float* __restrict__ m, int* __restrict__ cursor,
    int* __restrict__ inv, float4* __restrict__ vecm, int E)
{
    const int e = blockIdx.x * 1024 + threadIdx.x;
    if (e < E) {
        const int p = atomicAdd(&cursor[senders[e]], 1);
        inv[e] = p;
        float4 vm;
        vm.x = vectors[(size_t)e * 3 + 0];
        vm.y = vectors[(size_t)e * 3 + 1];
        vm.z = vectors[(size_t)e * 3 + 2];
        vm.w = m[e];
        vecm[p] = vm;
    }
}

// =====================================================================
// k_env: w = (x*m) @ WenvT via MFMA. 128 edges/block, 32KB LDS.
// Also exports the bf16 xm tile (xmb, linear) for k_mlp, and writes the
// w rows at SORTED positions for the streaming gather.
// =====================================================================
__global__ __launch_bounds__(512) void k_env(
    const float* __restrict__ x, const float* __restrict__ m,
    const char* __restrict__ wsb, const int* __restrict__ inv,
    char* __restrict__ wout, char* __restrict__ xmb, int E)
{
    __shared__ char lds[32768];  // xm [128][256B] swz; reused for bf16 results
    const int tid = threadIdx.x, l = tid & 63, wid = tid >> 6;
    const int lr = l & 15, lg = l >> 4;
    const int n0 = wid * 16;

    // WenvT fragments for this wave's 16 columns (loop-invariant)
    bf16x8 B[4];
    #pragma unroll
    for (int kk = 0; kk < 4; ++kk)
        B[kk] = *(const bf16x8*)(wsb + WS_WE + (n0 + lr) * 256 + kk * 64 + lg * 16);

    const int eb = blockIdx.x * 128;
    {   // xm tile: 4 threads/edge
        const int el = tid >> 2, q = tid & 3;
        const int e = eb + el;
        if (e < E) {
            const float mv = m[e];
            const float4* xp = (const float4*)&x[(size_t)e * 128 + q * 32];
            #pragma unroll
            for (int j = 0; j < 4; ++j) {
                float4 A = xp[2 * j], Bv = xp[2 * j + 1];
                int4 w;
                w.x = packbf(A.x * mv, A.y * mv); w.y = packbf(A.z * mv, A.w * mv);
                w.z = packbf(Bv.x * mv, Bv.y * mv); w.w = packbf(Bv.z * mv, Bv.w * mv);
                *(int4*)(lds + el * 256 + swz(el, q * 64 + j * 16)) = w;
            }
        } else {
            const int4 z = {0, 0, 0, 0};
            #pragma unroll
            for (int j = 0; j < 4; ++j)
                *(int4*)(lds + el * 256 + swz(el, q * 64 + j * 16)) = z;
        }
    }
    __syncthreads();

    {   // export xm bf16 (linear) for k_mlp; overlaps with MFMA below
        const int el = tid >> 2, q = tid & 3;
        const int e = eb + el;
        if (e < E) {
            int4* d = (int4*)(xmb + (size_t)e * 256 + q * 64);
            #pragma unroll
            for (int j = 0; j < 4; ++j)
                d[j] = *(int4*)(lds + el * 256 + ((q * 64 + j * 16) ^ ((el & 7) << 4)));
        }
    }

    f32x4 acc[8];
    #pragma unroll
    for (int a = 0; a < 8; ++a) acc[a] = (f32x4){0.f, 0.f, 0.f, 0.f};

    #pragma unroll
    for (int kk = 0; kk < 4; ++kk) {
        const int kb = kk * 64 + lg * 16;
        #pragma unroll
        for (int mt = 0; mt < 8; ++mt) {
            const int row = mt * 16 + lr;
            bf16x8 a = *(const bf16x8*)(lds + row * 256 + swz(row, kb));
            acc[mt] = __builtin_amdgcn_mfma_f32_16x16x32_bf16(a, B[kk], acc[mt], 0, 0, 0);
        }
    }
    __syncthreads();   // all A-reads done; reuse buffer for results

    #pragma unroll
    for (int mt = 0; mt < 8; ++mt)
        #pragma unroll
        for (int r = 0; r < 4; ++r) {
            const int row = mt * 16 + lg * 4 + r;
            *(unsigned short*)(lds + row * 256 + (((n0 + lr) * 2) ^ ((row & 7) << 4))) =
                bf16r(acc[mt][r]);
        }
    __syncthreads();

    {   // copy-out to SORTED position p = inv[e]
        const int el = tid >> 2, q = tid & 3;
        const int e = eb + el;
        if (e < E) {
            const int p = inv[e];
            int4* d = (int4*)(wout + (size_t)p * 256 + q * 64);
            #pragma unroll
            for (int j = 0; j < 4; ++j)
                d[j] = *(int4*)(lds + el * 256 + ((q * 64 + j * 16) ^ ((el & 7) << 4)));
        }
    }
}

// =====================================================================
// k_gather: one wave per node; STREAMING reads of sorted w rows and
// vecm; write node accumulators once (no atomics).
// =====================================================================
__global__ __launch_bounds__(256) void k_gather(
    const char* __restrict__ wvb, const float4* __restrict__ vecm,
    const int* __restrict__ counts, const int* __restrict__ offsets,
    float* __restrict__ node_cnt, float* __restrict__ node_s,
    float* __restrict__ node_v)
{
    const int l = threadIdx.x & 63, wid = threadIdx.x >> 6;
    const int n = blockIdx.x * 4 + wid;
    if (n >= NN_NODES) return;
    const int cnt = counts[n], base = offsets[n];

    float as = 0.f, a0 = 0.f, a1 = 0.f, a2 = 0.f, am = 0.f;
    for (int i = 0; i < cnt; ++i) {
        const unsigned int wv =
            *(const unsigned int*)(wvb + (size_t)(base + i) * 256 + l * 4);
        const float4 vm = vecm[base + i];
        const float rn = 1.7320508075688772f /
                         sqrtf(vm.x * vm.x + vm.y * vm.y + vm.z * vm.z);
        const float w0 = bflo(wv) * vm.w;
        const float c1 = bfhi(wv) * vm.w * rn;
        as += w0; am += vm.w;
        a0 += c1 * vm.x; a1 += c1 * vm.y; a2 += c1 * vm.z;
    }
    if (l == 0) node_cnt[n] = am;
    node_s[(size_t)n * 64 + l] = as;
    float* nv = &node_v[((size_t)n * 64 + l) * 3];
    nv[0] = a0; nv[1] = a1; nv[2] = a2;
}

// =====================================================================
// k_prep_vout: gather + s_a/s_b stash + V_in tile + MFMA V_out,
// LDS-staged coalesced writes.
// =====================================================================
__global__ __launch_bounds__(512) void k_prep_vout(
    const float* __restrict__ V, const int* __restrict__ senders,
    const float* __restrict__ node_cnt, const float* __restrict__ node_s,
    const float* __restrict__ node_v, const char* __restrict__ wsb,
    float* __restrict__ out_x, float* __restrict__ out_v, int E)
{
    __shared__ char lds[49152 + 16384];   // vin[192][128]bf16 swz | WoutT 16K
    const int tid = threadIdx.x, l = tid & 63, wid = tid >> 6;

    {
        const int4* src = (const int4*)(wsb + WS_WO);
        int4 a = src[tid * 2], b = src[tid * 2 + 1];
        ((int4*)(lds + 49152))[tid * 2]     = a;
        ((int4*)(lds + 49152))[tid * 2 + 1] = b;
    }

    const int eb = blockIdx.x * 64;
    #pragma unroll 2
    for (int i = 0; i < 8; ++i) {
        const int el = wid * 8 + i;
        const int e  = eb + el;
        float Vs = 0.f, Vv0 = 0.f, Vv1 = 0.f, Vv2 = 0.f;
        float wYs = 0.f, wv0 = 0.f, wv1 = 0.f, wv2 = 0.f;
        if (e < E) {
            Vs = V[(size_t)e * 256 + l];
            const float* vp = &V[(size_t)e * 256 + 64 + l * 3];
            Vv0 = vp[0]; Vv1 = vp[1]; Vv2 = vp[2];
            const int sn = senders[e];
            const float rden = 1.0f / (node_cnt[sn] + 1e-5f);
            wYs = node_s[(size_t)sn * 64 + l] * rden;
            const float* nvp = &node_v[((size_t)sn * 64 + l) * 3];
            wv0 = nvp[0] * rden; wv1 = nvp[1] * rden; wv2 = nvp[2] * rden;
            unsigned short* sab = (unsigned short*)((char*)out_x + (size_t)e * 512);
            sab[l]      = bf16r(wYs * Vs);
            sab[64 + l] = bf16r((wv0 * Vv0 + wv1 * Vv1 + wv2 * Vv2) * 0.57735026918962576f);
        }
        const float vvk[3] = {Vv0, Vv1, Vv2};
        const float wvk[3] = {wv0, wv1, wv2};
        #pragma unroll
        for (int k = 0; k < 3; ++k) {
            const int row = el * 3 + k;
            *(unsigned short*)(lds + row * 256 + swz(row, l * 2))       = bf16r(wYs * vvk[k]);
            *(unsigned short*)(lds + row * 256 + swz(row, 128 + l * 2)) = bf16r(wvk[k] * Vs);
        }
    }
    __syncthreads();

    const int wm = wid & 3, wn = wid >> 2;
    const int m0 = wm * 48, n0 = wn * 32;
    const int lr = l & 15, lg = l >> 4;
    f32x4 acc[3][2];
    #pragma unroll
    for (int a = 0; a < 3; ++a)
        #pragma unroll
        for (int b = 0; b < 2; ++b) acc[a][b] = (f32x4){0.f, 0.f, 0.f, 0.f};

    #pragma unroll
    for (int kk = 0; kk < 4; ++kk) {
        const int kb = kk * 64 + lg * 16;
        bf16x8 a0 = *(const bf16x8*)(lds + (m0 + lr) * 256      + swz(m0 + lr, kb));
        bf16x8 a1 = *(const bf16x8*)(lds + (m0 + 16 + lr) * 256 + swz(m0 + 16 + lr, kb));
        bf16x8 a2 = *(const bf16x8*)(lds + (m0 + 32 + lr) * 256 + swz(m0 + 32 + lr, kb));
        bf16x8 b0 = *(const bf16x8*)(lds + 49152 + (n0 + lr) * 256      + swz(n0 + lr, kb));
        bf16x8 b1 = *(const bf16x8*)(lds + 49152 + (n0 + 16 + lr) * 256 + swz(n0 + 16 + lr, kb));
        acc[0][0] = __builtin_amdgcn_mfma_f32_16x16x32_bf16(a0, b0, acc[0][0], 0, 0, 0);
        acc[0][1] = __builtin_amdgcn_mfma_f32_16x16x32_bf16(a0, b1, acc[0][1], 0, 0, 0);
        acc[1][0] = __builtin_amdgcn_mfma_f32_16x16x32_bf16(a1, b0, acc[1][0], 0, 0, 0);
        acc[1][1] = __builtin_amdgcn_mfma_f32_16x16x32_bf16(a1, b1, acc[1][1], 0, 0, 0);
        acc[2][0] = __builtin_amdgcn_mfma_f32_16x16x32_bf16(a2, b0, acc[2][0], 0, 0, 0);
        acc[2][1] = __builtin_amdgcn_mfma_f32_16x16x32_bf16(a2, b1, acc[2][1], 0, 0, 0);
    }
    __syncthreads();

    #pragma unroll
    for (int mt = 0; mt < 3; ++mt)
        #pragma unroll
        for (int nt = 0; nt < 2; ++nt)
            #pragma unroll
            for (int r = 0; r < 4; ++r) {
                const int mm = m0 + mt * 16 + lg * 4 + r;
                const int el2 = mm / 3, kd = mm - el2 * 3;
                const int o = n0 + nt * 16 + lr;
                *(float*)(lds + el2 * 768 + (o * 3 + kd) * 4) = acc[mt][nt][r];
            }
    __syncthreads();
    if (eb + 64 <= E) {
        const int4* s = (const int4*)lds;
        int4* d = (int4*)(out_v + (size_t)eb * 192);
        #pragma unroll
        for (int j = 0; j < 6; ++j) d[tid * 6 + j] = s[tid * 6 + j];
    } else {
        for (int idx = tid; idx < 64 * 192; idx += 512) {
            const int el2 = idx / 192;
            if (eb + el2 < E)
                out_v[(size_t)(eb + el2) * 192 + (idx % 192)] = *(float*)(lds + idx * 4);
        }
    }
}

// =====================================================================
// k_mlp: fused MLP via MFMA. 64 edges/block, 48KB LDS.
// Reads prepacked bf16 xm (xmb) — no f32 x re-read, no packbf.
// =====================================================================
__global__ __launch_bounds__(512, 4) void k_mlp(
    const char* __restrict__ xmb, const float* __restrict__ ug,
    const char* __restrict__ wsb, float* __restrict__ out_x,
    float inv_c, int E)
{
    __shared__ char lds[49152];  // [0,32K): xcat swz -> g -> f32 out; [32K,48K): h
    const int tid = threadIdx.x, l = tid & 63, wid = tid >> 6;
    const int lr = l & 15, lg = l >> 4;
    const int n0 = wid * 16;
    const int eb = blockIdx.x * 64;

    // W1T fragments for this wave's 16 cols (K=256)
    bf16x8 B1[8];
    #pragma unroll
    for (int kk = 0; kk < 8; ++kk)
        B1[kk] = *(const bf16x8*)(wsb + WS_W1 + (n0 + lr) * 512 + kk * 64 + lg * 16);

    {   // xcat prep: 8 threads/edge; xm from xmb, s_a/s_b from stash
        const int el = tid >> 3, q = tid & 7;
        const int e = eb + el;
        if (e < E) {
            const int4* xp = (const int4*)(xmb + (size_t)e * 256 + q * 32);
            *(int4*)(lds + el * 512 + swz(el, q * 32))      = xp[0];
            *(int4*)(lds + el * 512 + swz(el, q * 32 + 16)) = xp[1];
            const int4* sp = (const int4*)((const char*)out_x + (size_t)e * 512 + q * 32);
            *(int4*)(lds + el * 512 + swz(el, 256 + q * 32))      = sp[0];
            *(int4*)(lds + el * 512 + swz(el, 256 + q * 32 + 16)) = sp[1];
        } else {
            const int4 z = {0, 0, 0, 0};
            *(int4*)(lds + el * 512 + swz(el, q * 32))            = z;
            *(int4*)(lds + el * 512 + swz(el, q * 32 + 16))       = z;
            *(int4*)(lds + el * 512 + swz(el, 256 + q * 32))      = z;
            *(int4*)(lds + el * 512 + swz(el, 256 + q * 32 + 16)) = z;
        }
    }
    __syncthreads();

    // ---- stage 1: xcat[64x256] @ W1T ----
    f32x4 a1[4];
    #pragma unroll
    for (int a = 0; a < 4; ++a) a1[a] = (f32x4){0.f, 0.f, 0.f, 0.f};
    #pragma unroll
    for (int kk = 0; kk < 8; ++kk) {
        const int kb = kk * 64 + lg * 16;
        #pragma unroll
        for (int mt = 0; mt < 4; ++mt) {
            const int row = mt * 16 + lr;
            bf16x8 a = *(const bf16x8*)(lds + row * 512 + swz(row, kb));
            a1[mt] = __builtin_amdgcn_mfma_f32_16x16x32_bf16(a, B1[kk], a1[mt], 0, 0, 0);
        }
    }

    // load W2T/W3T fragments (L2-hot; latency hidden by h-write + barrier)
    bf16x8 B2[4], B3[4];
    #pragma unroll
    for (int kk = 0; kk < 4; ++kk) {
        B2[kk] = *(const bf16x8*)(wsb + WS_W2 + (n0 + lr) * 256 + kk * 64 + lg * 16);
        B3[kk] = *(const bf16x8*)(wsb + WS_W3 + (n0 + lr) * 256 + kk * 64 + lg * 16);
    }

    // write h (bf16) to lds+32K (disjoint from xcat; no barrier needed before)
    #pragma unroll
    for (int mt = 0; mt < 4; ++mt)
        #pragma unroll
        for (int r = 0; r < 4; ++r) {
            const int row = mt * 16 + lg * 4 + r;
            *(unsigned short*)(lds + 32768 + row * 256 + swz(row, (n0 + lr) * 2)) =
                bf16r(nsilu(a1[mt][r], inv_c));
        }
    __syncthreads();

    // ---- stage 2: h @ W2T ----
    f32x4 a2[4];
    #pragma unroll
    for (int a = 0; a < 4; ++a) a2[a] = (f32x4){0.f, 0.f, 0.f, 0.f};
    #pragma unroll
    for (int kk = 0; kk < 4; ++kk) {
        const int kb = kk * 64 + lg * 16;
        #pragma unroll
        for (int mt = 0; mt < 4; ++mt) {
            const int row = mt * 16 + lr;
            bf16x8 a = *(const bf16x8*)(lds + 32768 + row * 256 + swz(row, kb));
            a2[mt] = __builtin_amdgcn_mfma_f32_16x16x32_bf16(a, B2[kk], a2[mt], 0, 0, 0);
        }
    }
    // write g (bf16) into lds[0:16K) — xcat reads all finished (h barrier)
    #pragma unroll
    for (int mt = 0; mt < 4; ++mt)
        #pragma unroll
        for (int r = 0; r < 4; ++r) {
            const int row = mt * 16 + lg * 4 + r;
            *(unsigned short*)(lds + row * 256 + swz(row, (n0 + lr) * 2)) =
                bf16r(nsilu(a2[mt][r], inv_c));
        }
    __syncthreads();

    // ---- stage 3: g @ W3T ----
    f32x4 a3[4];
    #pragma unroll
    for (int a = 0; a < 4; ++a) a3[a] = (f32x4){0.f, 0.f, 0.f, 0.f};
    #pragma unroll
    for (int kk = 0; kk < 4; ++kk) {
        const int kb = kk * 64 + lg * 16;
        #pragma unroll
        for (int mt = 0; mt < 4; ++mt) {
            const int row = mt * 16 + lr;
            bf16x8 a = *(const bf16x8*)(lds + row * 256 + swz(row, kb));
            a3[mt] = __builtin_amdgcn_mfma_f32_16x16x32_bf16(a, B3[kk], a3[mt], 0, 0, 0);
        }
    }
    __syncthreads();   // all g reads done; reuse lds[0:32K) for f32 results

    #pragma unroll
    for (int mt = 0; mt < 4; ++mt)
        #pragma unroll
        for (int r = 0; r < 4; ++r) {
            const int row = mt * 16 + lg * 4 + r;
            *(float*)(lds + row * 512 + (((n0 + lr) * 4) ^ ((row & 7) << 4))) = a3[mt][r];
        }
    __syncthreads();

    {   // coalesced copy-out with u scaling
        const int el = tid >> 3, q = tid & 7;
        const int e = eb + el;
        if (e < E) {
            const float uu = ug[e];
            #pragma unroll
            for (int j = 0; j < 4; ++j) {
                int4 v = *(int4*)(lds + el * 512 + ((q * 64 + j * 16) ^ ((el & 7) << 4)));
                float4 f;
                f.x = __int_as_float(v.x) * uu; f.y = __int_as_float(v.y) * uu;
                f.z = __int_as_float(v.z) * uu; f.w = __int_as_float(v.w) * uu;
                *(float4*)(&out_x[(size_t)e * 128 + q * 16 + j * 4]) = f;
            }
        }
    }
}

// =====================================================================
extern "C" void kernel_launch(void* const* d_in, const int* in_sizes, int n_in,
                              void* d_out, int out_size, void* d_ws, size_t ws_size,
                              hipStream_t stream) {
    const float* vectors = (const float*)d_in[0];
    const float* x       = (const float*)d_in[1];
    const float* V       = (const float*)d_in[2];
    const float* u       = (const float*)d_in[3];
    const float* m       = (const float*)d_in[4];
    const float* W_env   = (const float*)d_in[5];
    const float* W1      = (const float*)d_in[6];
    const float* W2      = (const float*)d_in[7];
    const float* W3      = (const float*)d_in[8];
    const float* W_out   = (const float*)d_in[9];
    const int*   senders = (const int*)d_in[10];

    const int E = in_sizes[4];   // 256000

    char*  wsb      = (char*)d_ws;
    float* node_cnt = (float*)d_ws;
    float* node_s   = node_cnt + NN_NODES;
    float* node_v   = node_s + (size_t)NN_NODES * 64;
    int* counts  = (int*)(wsb + WS_COUNTS);
    int* offsets = (int*)(wsb + WS_OFFSETS);
    int* cursor  = (int*)(wsb + WS_CURSOR);
    int* inv     = (int*)(wsb + WS_INV);
    float4* vecm = (float4*)(wsb + WS_VECM);
    char* xmb    = wsb + WS_XMB;

    float* out_x = (float*)d_out;
    float* out_v = out_x + (size_t)E * 128;
    char*  wvb   = (char*)out_v;   // sorted w scratch lives in out_v region

    k_wprep<<<128, 256, 0, stream>>>(W1, W2, W3, W_out, W_env, wsb);
    k_hist<<<(E + 1023) / 1024, 1024, 0, stream>>>(senders, counts, E);
    k_scan<<<1, 1024, 0, stream>>>(counts, offsets, cursor);
    k_binfill<<<(E + 1023) / 1024, 1024, 0, stream>>>(senders, vectors, m,
                                                      cursor, inv, vecm, E);
    k_env<<<(E + 127) / 128, 512, 0, stream>>>(x, m, wsb, inv, wvb, xmb, E);
    k_gather<<<(NN_NODES + 3) / 4, 256, 0, stream>>>(wvb, vecm, counts, offsets,
                                                     node_cnt, node_s, node_v);
    k_prep_vout<<<(E + 63) / 64, 512, 0, stream>>>(V, senders, node_cnt, node_s,
                                                   node_v, wsb, out_x, out_v, E);
    k_mlp<<<(E + 63) / 64, 512, 0, stream>>>(xmb, u, wsb, out_x, INV_SILU_C, E);
}

// Round 8
// 439.839 us; speedup vs baseline: 1.1537x; 1.0198x over previous
//
#include <hip/hip_runtime.h>
#include <math.h>

typedef short bf16x8 __attribute__((ext_vector_type(8)));
typedef float f32x4 __attribute__((ext_vector_type(4)));

#define S128 0.08838834764831845f   /* 1/sqrt(128) */
#define S256I 0.0625f               /* 1/sqrt(256) */
#define NN_NODES 16000

// ws layout (bytes)
#define WS_COUNTS   16448000            /* int[16000] (node arrays occupy [0,16448000)) */
#define WS_OFFSETS  (WS_COUNTS + 64000)
#define WS_CURSOR   (WS_OFFSETS + 64000)
#define WS_INV      (WS_CURSOR + 64000) /* int[256000]: e -> sorted pos */
#define WS_W1 (WS_INV + 1024000)        /* W1T [128][256] bf16 unswizzled */
#define WS_W2 (WS_W1 + 65536)           /* W2T [128][128] bf16 unswizzled */
#define WS_W3 (WS_W2 + 32768)           /* W3T [128][128] bf16 unswizzled */
#define WS_WO (WS_W3 + 32768)           /* WoutT [64][128] bf16 swizzled (LDS-staged) */
#define WS_WE (WS_WO + 16384)           /* WenvT [128][128] bf16 unswizzled (reg-loaded) */
#define WS_VECM (WS_WE + 32768)         /* float4[256000]: sorted (vx,vy,vz,m) */
#define WS_XMB  (WS_VECM + 4096000)     /* bf16 xm [E][128] linear, 65.5MB */

// ---- host-side constant: SILU_C exactly as the reference computes it ----
static float compute_inv_silu_c() {
    double sum = 0.0, prev = 0.0;
    const double dz = 24.0 / 100000.0;
    for (int i = 0; i <= 100000; ++i) {
        double z = -12.0 + dz * (double)i;
        double pdf = exp(-0.5 * z * z) * 0.3989422804014327;
        double s = z / (1.0 + exp(-z));
        double f = s * s * pdf;
        if (i) sum += 0.5 * (prev + f) * dz;
        prev = f;
    }
    return (float)(1.0 / sqrt(sum));
}
static const float INV_SILU_C = compute_inv_silu_c();

// ---- device helpers ----
__device__ __forceinline__ unsigned int packbf(float a, float b) {
    union { float f; unsigned int u; } ca, cb;
    ca.f = a; cb.f = b;
    unsigned int ua = ca.u + (0x7fffu + ((ca.u >> 16) & 1u));
    unsigned int ub = cb.u + (0x7fffu + ((cb.u >> 16) & 1u));
    return (ua >> 16) | (ub & 0xffff0000u);
}
__device__ __forceinline__ unsigned short bf16r(float v) {
    union { float f; unsigned int u; } c; c.f = v;
    return (unsigned short)((c.u + (0x7fffu + ((c.u >> 16) & 1u))) >> 16);
}
__device__ __forceinline__ float bflo(unsigned int u) { return __uint_as_float(u << 16); }
__device__ __forceinline__ float bfhi(unsigned int u) { return __uint_as_float(u & 0xffff0000u); }
__device__ __forceinline__ int swz(int row, int b) { return b ^ ((row & 7) << 4); }
__device__ __forceinline__ float nsilu(float v, float ic) {
    return v / (1.0f + __expf(-v)) * ic;
}

// =====================================================================
// k_wprep: bf16-quantize + transpose weights into ws; zero counts[].
// =====================================================================
__global__ __launch_bounds__(256) void k_wprep(
    const float* __restrict__ W1, const float* __restrict__ W2,
    const float* __restrict__ W3, const float* __restrict__ Wout,
    const float* __restrict__ Wenv, char* __restrict__ wsb)
{
    const int t = blockIdx.x * 256 + threadIdx.x;   // 32768 threads
    if (t < NN_NODES) ((int*)(wsb + WS_COUNTS))[t] = 0;
    if (t < 32768) {  // W1T[128][256]
        int n = t & 127, k = t >> 7;
        *(unsigned short*)(wsb + WS_W1 + n * 512 + k * 2) =
            bf16r(W1[k * 128 + n] * S256I);
    }
    if (t < 16384) {  // W2T, W3T [128][128]
        int n = t & 127, k = t >> 7;
        *(unsigned short*)(wsb + WS_W2 + n * 256 + k * 2) =
            bf16r(W2[k * 128 + n] * S128);
        *(unsigned short*)(wsb + WS_W3 + n * 256 + k * 2) =
            bf16r(W3[k * 128 + n] * S128);
    }
    if (t < 16384) {  // WenvT[128][128], interleaved row perm (w0/w1 pairs)
        int j = t & 127, k = t >> 7;
        int c = (j & 1) ? 64 + (j >> 1) : (j >> 1);
        *(unsigned short*)(wsb + WS_WE + j * 256 + k * 2) =
            bf16r(Wenv[k * 128 + c] * S128);
    }
    if (t < 8192) {   // WoutT[64][128] swizzled
        int o = t & 63, uu = t >> 6;
        *(unsigned short*)(wsb + WS_WO + o * 256 + ((uu * 2) ^ ((o & 7) << 4))) =
            bf16r(Wout[uu * 64 + o] * S128);
    }
}

// =====================================================================
// sort-by-sender chain
// =====================================================================
__global__ __launch_bounds__(1024) void k_hist(
    const int* __restrict__ senders, int* __restrict__ counts, int E)
{
    const int e = blockIdx.x * 1024 + threadIdx.x;
    if (e < E) atomicAdd(&counts[senders[e]], 1);
}

__global__ __launch_bounds__(1024) void k_scan(
    const int* __restrict__ counts, int* __restrict__ offsets,
    int* __restrict__ cursor)
{
    __shared__ int part[1024];
    const int t = threadIdx.x;
    const int s0 = t * 16;
    const int s1 = (s0 + 16 < NN_NODES) ? s0 + 16 : NN_NODES;
    int s = 0;
    for (int i = s0; i < s1; ++i) s += counts[i];
    part[t] = s;
    __syncthreads();
    for (int off = 1; off < 1024; off <<= 1) {
        int v = part[t];
        if (t >= off) v += part[t - off];
        __syncthreads();
        part[t] = v;
        __syncthreads();
    }
    int run = t ? part[t - 1] : 0;
    for (int i = s0; i < s1; ++i) {
        offsets[i] = run; cursor[i] = run; run += counts[i];
    }
}

// binfill: assign sorted position p per edge; emit inv[e]=p and
// vecm_sorted[p]=(vx,vy,vz,m) so the gather is fully streaming.
__global__ __launch_bounds__(1024) void k_binfill(
    const int* __restrict__ senders, const float* __restrict__ vectors,
    const float* __restrict__ m, int* __restrict__ cursor,
    int* __restrict__ inv, float4* __restrict__ vecm, int E)
{
    const int e = blockIdx.x * 1024 + threadIdx.x;
    if (e < E) {
        const int p = atomicAdd(&cursor[senders[e]], 1);
        inv[e] = p;
        float4 vm;
        vm.x = vectors[(size_t)e * 3 + 0];
        vm.y = vectors[(size_t)e * 3 + 1];
        vm.z = vectors[(size_t)e * 3 + 2];
        vm.w = m[e];
        vecm[p] = vm;
    }
}

// =====================================================================
// k_env: w = (x*m) @ WenvT via MFMA. 128 edges/block, 32KB LDS.
// Exports bf16 xm (linear) for k_fuse; writes w rows at SORTED positions.
// =====================================================================
__global__ __launch_bounds__(512) void k_env(
    const float* __restrict__ x, const float* __restrict__ m,
    const char* __restrict__ wsb, const int* __restrict__ inv,
    char* __restrict__ wout, char* __restrict__ xmb, int E)
{
    __shared__ char lds[32768];  // xm [128][256B] swz; reused for bf16 results
    const int tid = threadIdx.x, l = tid & 63, wid = tid >> 6;
    const int lr = l & 15, lg = l >> 4;
    const int n0 = wid * 16;

    // WenvT fragments for this wave's 16 columns (loop-invariant)
    bf16x8 B[4];
    #pragma unroll
    for (int kk = 0; kk < 4; ++kk)
        B[kk] = *(const bf16x8*)(wsb + WS_WE + (n0 + lr) * 256 + kk * 64 + lg * 16);

    const int eb = blockIdx.x * 128;
    {   // xm tile: 4 threads/edge
        const int el = tid >> 2, q = tid & 3;
        const int e = eb + el;
        if (e < E) {
            const float mv = m[e];
            const float4* xp = (const float4*)&x[(size_t)e * 128 + q * 32];
            #pragma unroll
            for (int j = 0; j < 4; ++j) {
                float4 A = xp[2 * j], Bv = xp[2 * j + 1];
                int4 w;
                w.x = packbf(A.x * mv, A.y * mv); w.y = packbf(A.z * mv, A.w * mv);
                w.z = packbf(Bv.x * mv, Bv.y * mv); w.w = packbf(Bv.z * mv, Bv.w * mv);
                *(int4*)(lds + el * 256 + swz(el, q * 64 + j * 16)) = w;
            }
        } else {
            const int4 z = {0, 0, 0, 0};
            #pragma unroll
            for (int j = 0; j < 4; ++j)
                *(int4*)(lds + el * 256 + swz(el, q * 64 + j * 16)) = z;
        }
    }
    __syncthreads();

    {   // export xm bf16 (linear) for k_fuse
        const int el = tid >> 2, q = tid & 3;
        const int e = eb + el;
        if (e < E) {
            int4* d = (int4*)(xmb + (size_t)e * 256 + q * 64);
            #pragma unroll
            for (int j = 0; j < 4; ++j)
                d[j] = *(int4*)(lds + el * 256 + ((q * 64 + j * 16) ^ ((el & 7) << 4)));
        }
    }

    f32x4 acc[8];
    #pragma unroll
    for (int a = 0; a < 8; ++a) acc[a] = (f32x4){0.f, 0.f, 0.f, 0.f};

    #pragma unroll
    for (int kk = 0; kk < 4; ++kk) {
        const int kb = kk * 64 + lg * 16;
        #pragma unroll
        for (int mt = 0; mt < 8; ++mt) {
            const int row = mt * 16 + lr;
            bf16x8 a = *(const bf16x8*)(lds + row * 256 + swz(row, kb));
            acc[mt] = __builtin_amdgcn_mfma_f32_16x16x32_bf16(a, B[kk], acc[mt], 0, 0, 0);
        }
    }
    __syncthreads();   // all A-reads done; reuse buffer for results

    #pragma unroll
    for (int mt = 0; mt < 8; ++mt)
        #pragma unroll
        for (int r = 0; r < 4; ++r) {
            const int row = mt * 16 + lg * 4 + r;
            *(unsigned short*)(lds + row * 256 + (((n0 + lr) * 2) ^ ((row & 7) << 4))) =
                bf16r(acc[mt][r]);
        }
    __syncthreads();

    {   // copy-out to SORTED position p = inv[e]
        const int el = tid >> 2, q = tid & 3;
        const int e = eb + el;
        if (e < E) {
            const int p = inv[e];
            int4* d = (int4*)(wout + (size_t)p * 256 + q * 64);
            #pragma unroll
            for (int j = 0; j < 4; ++j)
                d[j] = *(int4*)(lds + el * 256 + ((q * 64 + j * 16) ^ ((el & 7) << 4)));
        }
    }
}

// =====================================================================
// k_gather: one wave per node; STREAMING reads of sorted w rows and
// vecm; write node accumulators once (no atomics).
// =====================================================================
__global__ __launch_bounds__(256) void k_gather(
    const char* __restrict__ wvb, const float4* __restrict__ vecm,
    const int* __restrict__ counts, const int* __restrict__ offsets,
    float* __restrict__ node_cnt, float* __restrict__ node_s,
    float* __restrict__ node_v)
{
    const int l = threadIdx.x & 63, wid = threadIdx.x >> 6;
    const int n = blockIdx.x * 4 + wid;
    if (n >= NN_NODES) return;
    const int cnt = counts[n], base = offsets[n];

    float as = 0.f, a0 = 0.f, a1 = 0.f, a2 = 0.f, am = 0.f;
    for (int i = 0; i < cnt; ++i) {
        const unsigned int wv =
            *(const unsigned int*)(wvb + (size_t)(base + i) * 256 + l * 4);
        const float4 vm = vecm[base + i];
        const float rn = 1.7320508075688772f /
                         sqrtf(vm.x * vm.x + vm.y * vm.y + vm.z * vm.z);
        const float w0 = bflo(wv) * vm.w;
        const float c1 = bfhi(wv) * vm.w * rn;
        as += w0; am += vm.w;
        a0 += c1 * vm.x; a1 += c1 * vm.y; a2 += c1 * vm.z;
    }
    if (l == 0) node_cnt[n] = am;
    node_s[(size_t)n * 64 + l] = as;
    float* nv = &node_v[((size_t)n * 64 + l) * 3];
    nv[0] = a0; nv[1] = a1; nv[2] = a2;
}

// =====================================================================
// k_fuse: merged prep_vout + MLP. 64 edges/block, 512 threads, 80KB LDS.
// Phase A: gather + s_a/s_b (LDS stash) + V_in tile + MFMA V_out.
// Phase B: xcat = [xm | s_a | s_b] -> W1 -> nsilu -> W2 -> nsilu -> W3 -> *u.
// LDS: [0:48K) vin/results/xcat/g/out | [48K:64K) WoutT | [64K:80K) sab
// =====================================================================
__global__ __launch_bounds__(512, 4) void k_fuse(
    const float* __restrict__ V, const int* __restrict__ senders,
    const float* __restrict__ node_cnt, const float* __restrict__ node_s,
    const float* __restrict__ node_v, const char* __restrict__ wsb,
    const char* __restrict__ xmb, const float* __restrict__ ug,
    float* __restrict__ out_x, float* __restrict__ out_v,
    float inv_c, int E)
{
    __shared__ char lds[81920];
    const int tid = threadIdx.x, l = tid & 63, wid = tid >> 6;
    const int lr = l & 15, lg = l >> 4;

    {   // stage WoutT (pre-swizzled) -> [48K:64K)
        const int4* src = (const int4*)(wsb + WS_WO);
        ((int4*)(lds + 49152))[tid * 2]     = src[tid * 2];
        ((int4*)(lds + 49152))[tid * 2 + 1] = src[tid * 2 + 1];
    }

    const int eb = blockIdx.x * 64;
    // ---- phase A: per-edge gather; build vin tile + sab stash ----
    #pragma unroll 2
    for (int i = 0; i < 8; ++i) {
        const int el = wid * 8 + i;
        const int e  = eb + el;
        float Vs = 0.f, Vv0 = 0.f, Vv1 = 0.f, Vv2 = 0.f;
        float wYs = 0.f, wv0 = 0.f, wv1 = 0.f, wv2 = 0.f;
        if (e < E) {
            Vs = V[(size_t)e * 256 + l];
            const float* vp = &V[(size_t)e * 256 + 64 + l * 3];
            Vv0 = vp[0]; Vv1 = vp[1]; Vv2 = vp[2];
            const int sn = senders[e];
            const float rden = 1.0f / (node_cnt[sn] + 1e-5f);
            wYs = node_s[(size_t)sn * 64 + l] * rden;
            const float* nvp = &node_v[((size_t)sn * 64 + l) * 3];
            wv0 = nvp[0] * rden; wv1 = nvp[1] * rden; wv2 = nvp[2] * rden;
        }
        // sab stash (s_a | s_b), bf16, 256B/edge
        *(unsigned short*)(lds + 65536 + el * 256 + l * 2) = bf16r(wYs * Vs);
        *(unsigned short*)(lds + 65536 + el * 256 + 128 + l * 2) =
            bf16r((wv0 * Vv0 + wv1 * Vv1 + wv2 * Vv2) * 0.57735026918962576f);
        // vin rows 3*el+k: cols [0,64)=v_a (u=l), [64,128)=v_b (u=64+l)
        const float vvk[3] = {Vv0, Vv1, Vv2};
        const float wvk[3] = {wv0, wv1, wv2};
        #pragma unroll
        for (int k = 0; k < 3; ++k) {
            const int row = el * 3 + k;
            *(unsigned short*)(lds + row * 256 + swz(row, l * 2))       = bf16r(wYs * vvk[k]);
            *(unsigned short*)(lds + row * 256 + swz(row, 128 + l * 2)) = bf16r(wvk[k] * Vs);
        }
    }
    __syncthreads();

    // ---- V_out GEMM: waves 4x2; wave = 3 m-tiles x 2 n-tiles ----
    {
        const int wm = wid & 3, wn = wid >> 2;
        const int m0 = wm * 48, n0v = wn * 32;
        f32x4 acc[3][2];
        #pragma unroll
        for (int a = 0; a < 3; ++a)
            #pragma unroll
            for (int b = 0; b < 2; ++b) acc[a][b] = (f32x4){0.f, 0.f, 0.f, 0.f};

        #pragma unroll
        for (int kk = 0; kk < 4; ++kk) {
            const int kb = kk * 64 + lg * 16;
            bf16x8 a0 = *(const bf16x8*)(lds + (m0 + lr) * 256      + swz(m0 + lr, kb));
            bf16x8 a1 = *(const bf16x8*)(lds + (m0 + 16 + lr) * 256 + swz(m0 + 16 + lr, kb));
            bf16x8 a2 = *(const bf16x8*)(lds + (m0 + 32 + lr) * 256 + swz(m0 + 32 + lr, kb));
            bf16x8 b0 = *(const bf16x8*)(lds + 49152 + (n0v + lr) * 256      + swz(n0v + lr, kb));
            bf16x8 b1 = *(const bf16x8*)(lds + 49152 + (n0v + 16 + lr) * 256 + swz(n0v + 16 + lr, kb));
            acc[0][0] = __builtin_amdgcn_mfma_f32_16x16x32_bf16(a0, b0, acc[0][0], 0, 0, 0);
            acc[0][1] = __builtin_amdgcn_mfma_f32_16x16x32_bf16(a0, b1, acc[0][1], 0, 0, 0);
            acc[1][0] = __builtin_amdgcn_mfma_f32_16x16x32_bf16(a1, b0, acc[1][0], 0, 0, 0);
            acc[1][1] = __builtin_amdgcn_mfma_f32_16x16x32_bf16(a1, b1, acc[1][1], 0, 0, 0);
            acc[2][0] = __builtin_amdgcn_mfma_f32_16x16x32_bf16(a2, b0, acc[2][0], 0, 0, 0);
            acc[2][1] = __builtin_amdgcn_mfma_f32_16x16x32_bf16(a2, b1, acc[2][1], 0, 0, 0);
        }
        __syncthreads();   // all vin reads done; reuse [0:48K) as f32 result tile

        #pragma unroll
        for (int mt = 0; mt < 3; ++mt)
            #pragma unroll
            for (int nt = 0; nt < 2; ++nt)
                #pragma unroll
                for (int r = 0; r < 4; ++r) {
                    const int mm = m0 + mt * 16 + lg * 4 + r;
                    const int el2 = mm / 3, kd = mm - el2 * 3;
                    const int o = n0v + nt * 16 + lr;
                    *(float*)(lds + el2 * 768 + (o * 3 + kd) * 4) = acc[mt][nt][r];
                }
    }
    __syncthreads();
    if (eb + 64 <= E) {   // coalesced 48KB copy-out
        const int4* s = (const int4*)lds;
        int4* d = (int4*)(out_v + (size_t)eb * 192);
        #pragma unroll
        for (int j = 0; j < 6; ++j) d[tid * 6 + j] = s[tid * 6 + j];
    } else {
        for (int idx = tid; idx < 64 * 192; idx += 512) {
            const int el2 = idx / 192;
            if (eb + el2 < E)
                out_v[(size_t)(eb + el2) * 192 + (idx % 192)] = *(float*)(lds + idx * 4);
        }
    }
    __syncthreads();   // copy-out reads done; [0:48K) free for phase B

    // ---- phase B: MLP ----
    const int n0 = wid * 16;
    bf16x8 B1[8];
    #pragma unroll
    for (int kk = 0; kk < 8; ++kk)
        B1[kk] = *(const bf16x8*)(wsb + WS_W1 + (n0 + lr) * 512 + kk * 64 + lg * 16);

    {   // xcat build: 8 threads/edge; xm from xmb, s_a/s_b from sab stash
        const int el = tid >> 3, q = tid & 7;
        const int e = eb + el;
        int4 x0, x1;
        if (e < E) {
            const int4* xp = (const int4*)(xmb + (size_t)e * 256 + q * 32);
            x0 = xp[0]; x1 = xp[1];
        } else {
            x0 = (int4){0, 0, 0, 0}; x1 = (int4){0, 0, 0, 0};
        }
        *(int4*)(lds + el * 512 + swz(el, q * 32))      = x0;
        *(int4*)(lds + el * 512 + swz(el, q * 32 + 16)) = x1;
        int4 s0 = *(int4*)(lds + 65536 + el * 256 + q * 32);
        int4 s1 = *(int4*)(lds + 65536 + el * 256 + q * 32 + 16);
        *(int4*)(lds + el * 512 + swz(el, 256 + q * 32))      = s0;
        *(int4*)(lds + el * 512 + swz(el, 256 + q * 32 + 16)) = s1;
    }
    __syncthreads();

    // stage 1: xcat[64x256] @ W1T
    f32x4 a1[4];
    #pragma unroll
    for (int a = 0; a < 4; ++a) a1[a] = (f32x4){0.f, 0.f, 0.f, 0.f};
    #pragma unroll
    for (int kk = 0; kk < 8; ++kk) {
        const int kb = kk * 64 + lg * 16;
        #pragma unroll
        for (int mt = 0; mt < 4; ++mt) {
            const int row = mt * 16 + lr;
            bf16x8 a = *(const bf16x8*)(lds + row * 512 + swz(row, kb));
            a1[mt] = __builtin_amdgcn_mfma_f32_16x16x32_bf16(a, B1[kk], a1[mt], 0, 0, 0);
        }
    }

    // load W2T/W3T fragments (L2-hot; latency hidden by h-write + barrier)
    bf16x8 B2[4], B3[4];
    #pragma unroll
    for (int kk = 0; kk < 4; ++kk) {
        B2[kk] = *(const bf16x8*)(wsb + WS_W2 + (n0 + lr) * 256 + kk * 64 + lg * 16);
        B3[kk] = *(const bf16x8*)(wsb + WS_W3 + (n0 + lr) * 256 + kk * 64 + lg * 16);
    }

    // write h (bf16) to [32K:48K) (disjoint from xcat rows 0..63 = [0:32K))
    #pragma unroll
    for (int mt = 0; mt < 4; ++mt)
        #pragma unroll
        for (int r = 0; r < 4; ++r) {
            const int row = mt * 16 + lg * 4 + r;
            *(unsigned short*)(lds + 32768 + row * 256 + swz(row, (n0 + lr) * 2)) =
                bf16r(nsilu(a1[mt][r], inv_c));
        }
    __syncthreads();

    // stage 2: h @ W2T
    f32x4 a2[4];
    #pragma unroll
    for (int a = 0; a < 4; ++a) a2[a] = (f32x4){0.f, 0.f, 0.f, 0.f};
    #pragma unroll
    for (int kk = 0; kk < 4; ++kk) {
        const int kb = kk * 64 + lg * 16;
        #pragma unroll
        for (int mt = 0; mt < 4; ++mt) {
            const int row = mt * 16 + lr;
            bf16x8 a = *(const bf16x8*)(lds + 32768 + row * 256 + swz(row, kb));
            a2[mt] = __builtin_amdgcn_mfma_f32_16x16x32_bf16(a, B2[kk], a2[mt], 0, 0, 0);
        }
    }
    // write g (bf16) into [0:16K) — xcat reads all finished (h barrier)
    #pragma unroll
    for (int mt = 0; mt < 4; ++mt)
        #pragma unroll
        for (int r = 0; r < 4; ++r) {
            const int row = mt * 16 + lg * 4 + r;
            *(unsigned short*)(lds + row * 256 + swz(row, (n0 + lr) * 2)) =
                bf16r(nsilu(a2[mt][r], inv_c));
        }
    __syncthreads();

    // stage 3: g @ W3T
    f32x4 a3[4];
    #pragma unroll
    for (int a = 0; a < 4; ++a) a3[a] = (f32x4){0.f, 0.f, 0.f, 0.f};
    #pragma unroll
    for (int kk = 0; kk < 4; ++kk) {
        const int kb = kk * 64 + lg * 16;
        #pragma unroll
        for (int mt = 0; mt < 4; ++mt) {
            const int row = mt * 16 + lr;
            bf16x8 a = *(const bf16x8*)(lds + row * 256 + swz(row, kb));
            a3[mt] = __builtin_amdgcn_mfma_f32_16x16x32_bf16(a, B3[kk], a3[mt], 0, 0, 0);
        }
    }
    __syncthreads();   // all g reads done; reuse [0:32K) for f32 results

    #pragma unroll
    for (int mt = 0; mt < 4; ++mt)
        #pragma unroll
        for (int r = 0; r < 4; ++r) {
            const int row = mt * 16 + lg * 4 + r;
            *(float*)(lds + row * 512 + (((n0 + lr) * 4) ^ ((row & 7) << 4))) = a3[mt][r];
        }
    __syncthreads();

    {   // coalesced copy-out with u scaling
        const int el = tid >> 3, q = tid & 7;
        const int e = eb + el;
        if (e < E) {
            const float uu = ug[e];
            #pragma unroll
            for (int j = 0; j < 4; ++j) {
                int4 v = *(int4*)(lds + el * 512 + ((q * 64 + j * 16) ^ ((el & 7) << 4)));
                float4 f;
                f.x = __int_as_float(v.x) * uu; f.y = __int_as_float(v.y) * uu;
                f.z = __int_as_float(v.z) * uu; f.w = __int_as_float(v.w) * uu;
                *(float4*)(&out_x[(size_t)e * 128 + q * 16 + j * 4]) = f;
            }
        }
    }
}

// =====================================================================
extern "C" void kernel_launch(void* const* d_in, const int* in_sizes, int n_in,
                              void* d_out, int out_size, void* d_ws, size_t ws_size,
                              hipStream_t stream) {
    const float* vectors = (const float*)d_in[0];
    const float* x       = (const float*)d_in[1];
    const float* V       = (const float*)d_in[2];
    const float* u       = (const float*)d_in[3];
    const float* m       = (const float*)d_in[4];
    const float* W_env   = (const float*)d_in[5];
    const float* W1      = (const float*)d_in[6];
    const float* W2      = (const float*)d_in[7];
    const float* W3      = (const float*)d_in[8];
    const float* W_out   = (const float*)d_in[9];
    const int*   senders = (const int*)d_in[10];

    const int E = in_sizes[4];   // 256000

    char*  wsb      = (char*)d_ws;
    float* node_cnt = (float*)d_ws;
    float* node_s   = node_cnt + NN_NODES;
    float* node_v   = node_s + (size_t)NN_NODES * 64;
    int* counts  = (int*)(wsb + WS_COUNTS);
    int* offsets = (int*)(wsb + WS_OFFSETS);
    int* cursor  = (int*)(wsb + WS_CURSOR);
    int* inv     = (int*)(wsb + WS_INV);
    float4* vecm = (float4*)(wsb + WS_VECM);
    char* xmb    = wsb + WS_XMB;

    float* out_x = (float*)d_out;
    float* out_v = out_x + (size_t)E * 128;
    char*  wvb   = (char*)out_v;   // sorted w scratch lives in out_v region

    k_wprep<<<128, 256, 0, stream>>>(W1, W2, W3, W_out, W_env, wsb);
    k_hist<<<(E + 1023) / 1024, 1024, 0, stream>>>(senders, counts, E);
    k_scan<<<1, 1024, 0, stream>>>(counts, offsets, cursor);
    k_binfill<<<(E + 1023) / 1024, 1024, 0, stream>>>(senders, vectors, m,
                                                      cursor, inv, vecm, E);
    k_env<<<(E + 127) / 128, 512, 0, stream>>>(x, m, wsb, inv, wvb, xmb, E);
    k_gather<<<(NN_NODES + 3) / 4, 256, 0, stream>>>(wvb, vecm, counts, offsets,
                                                     node_cnt, node_s, node_v);
    k_fuse<<<(E + 63) / 64, 512, 0, stream>>>(V, senders, node_cnt, node_s,
                                              node_v, wsb, xmb, u,
                                              out_x, out_v, INV_SILU_C, E);
}